// Round 6
// baseline (1321.874 us; speedup 1.0000x reference)
//
#include <hip/hip_runtime.h>
#include <stdint.h>

// ---------------- problem constants ----------------
#define B_    16
#define C1_   512
#define C2_   1024
#define H2_   14
#define D_    1536
#define P_    784          // 28*28
#define N_    12544        // B_*P_
#define M_    15000
#define MPAD_ 15104        // padded bank rows
#define MT1_  118          // 128-wide m tiles (k_gexact)
#define MT2_  59           // 256-wide m tiles (k_gemm1)
#define NT_   98           // patch tiles of 128
#define IMG_  224
#define KS_   33

typedef unsigned short u16;
typedef unsigned int   u32;
typedef unsigned long long u64;

// ---------------- helpers ----------------
__device__ __forceinline__ u16 f2bf(float x) {
    u32 u = __float_as_uint(x);
    u = u + 0x7fffu + ((u >> 16) & 1u);   // RNE
    return (u16)(u >> 16);
}
__device__ __forceinline__ float bf2f(u16 h) {
    return __uint_as_float(((u32)h) << 16);
}
__device__ __forceinline__ u32 ordf(float f) {
    u32 u = __float_as_uint(f);
    return (u & 0x80000000u) ? ~u : (u | 0x80000000u);
}
__device__ __forceinline__ float unordf(u32 o) {
    u32 u = (o & 0x80000000u) ? (o ^ 0x80000000u) : ~o;
    return __uint_as_float(u);
}

// ---------------- avg-pool feat2 -> pooled2 [16,1024,14,14] ----------------
__global__ void k_pool2(const float* __restrict__ feat2, float* __restrict__ pooled2) {
    int idx = blockIdx.x * 256 + threadIdx.x;
    if (idx >= B_ * C2_ * H2_ * H2_) return;
    int x = idx % 14, y = (idx / 14) % 14, bc = idx / 196;
    const float* src = feat2 + (size_t)bc * 196;
    float s = 0.f;
    for (int dy = -1; dy <= 1; ++dy) {
        int yy = y + dy; if (yy < 0 || yy > 13) continue;
        for (int dx = -1; dx <= 1; ++dx) {
            int xx = x + dx; if (xx < 0 || xx > 13) continue;
            s += src[yy * 14 + xx];
        }
    }
    pooled2[idx] = s * (1.f / 9.f);
}

// ---------------- bank split (hi/lo bf16) + norms, vectorized ----------------
__global__ __launch_bounds__(192)
void k_bank(const float* __restrict__ bank, u16* __restrict__ Bh,
            u16* __restrict__ Bl, float* __restrict__ ynorm) {
    int m = blockIdx.x, tid = threadIdx.x;
    float nrm = 0.f;
    float v[8];
    if (m < M_) {
        const float4* src = (const float4*)(bank + (size_t)m * D_ + tid * 8);
        float4 a = src[0], b = src[1];
        v[0]=a.x; v[1]=a.y; v[2]=a.z; v[3]=a.w; v[4]=b.x; v[5]=b.y; v[6]=b.z; v[7]=b.w;
#pragma unroll
        for (int i = 0; i < 8; ++i) nrm += v[i] * v[i];
    } else {
#pragma unroll
        for (int i = 0; i < 8; ++i) v[i] = 0.f;
    }
    u32 hw[4], lw[4];
#pragma unroll
    for (int i = 0; i < 4; ++i) {
        u16 h0 = f2bf(v[2*i]),   l0 = f2bf(v[2*i]   - bf2f(h0));
        u16 h1 = f2bf(v[2*i+1]), l1 = f2bf(v[2*i+1] - bf2f(h1));
        hw[i] = (u32)h0 | ((u32)h1 << 16);
        lw[i] = (u32)l0 | ((u32)l1 << 16);
    }
    *(uint4*)(Bh + (size_t)m * D_ + tid * 8) = make_uint4(hw[0], hw[1], hw[2], hw[3]);
    *(uint4*)(Bl + (size_t)m * D_ + tid * 8) = make_uint4(lw[0], lw[1], lw[2], lw[3]);
    __shared__ float red[3];
    for (int off = 32; off; off >>= 1) nrm += __shfl_down(nrm, off, 64);
    int wave = tid >> 6, lane = tid & 63;
    if (lane == 0) red[wave] = nrm;
    __syncthreads();
    if (tid == 0) {
        float t = red[0] + red[1] + red[2];
        ynorm[m] = (m < M_) ? t : __uint_as_float(0x7f800000u);  // +inf pad
    }
}

// ---------------- embedding build, row-block version ----------------
__global__ __launch_bounds__(256)
void k_embed(const float* __restrict__ feat1, const float* __restrict__ pooled2,
             u16* __restrict__ Ah, u16* __restrict__ Al, float* __restrict__ xnorm) {
    __shared__ float sF[3 * 64 * 29];   // [r][c][x] padded to 29
    __shared__ float xn[28];
    const int tid = threadIdx.x, lane = tid & 63, wave = tid >> 6;
    const int b = blockIdx.x / 28, y = blockIdx.x % 28;
    const int brow = b * P_ + y * 28;
    if (tid < 28) xn[tid] = 0.f;

    float sy = y * 0.5f - 0.25f;
    int iy = (int)floorf(sy);
    float fy = sy - iy;
    int y0 = min(max(iy, 0), 13), y1 = min(max(iy + 1, 0), 13);
    __syncthreads();

    for (int cc = 0; cc < 8; ++cc) {
        for (int j = tid; j < 3 * 64 * 28; j += 256) {
            int x = j % 28, c = (j / 28) % 64, r = j / (28 * 64);
            int yy = y - 1 + r;
            float v = 0.f;
            if (yy >= 0 && yy < 28)
                v = feat1[((size_t)(b * C1_ + cc * 64 + c)) * 784 + yy * 28 + x];
            sF[(r * 64 + c) * 29 + x] = v;
        }
        __syncthreads();
        for (int it = 0; it < 7; ++it) {
            int x = it * 4 + wave, c = lane;
            float s = 0.f;
#pragma unroll
            for (int r = 0; r < 3; ++r) {
                int base = (r * 64 + c) * 29;
                if (x > 0) s += sF[base + x - 1];
                s += sF[base + x];
                if (x < 27) s += sF[base + x + 1];
            }
            float v = s * (1.f / 9.f);
            int col = cc * 64 + c;
            size_t off = (size_t)(brow + x) * D_ + col;
            u16 h = f2bf(v);
            Ah[off] = h; Al[off] = f2bf(v - bf2f(h));
            float vv = v * v;
            for (int m = 1; m < 64; m <<= 1) vv += __shfl_xor(vv, m, 64);
            if (lane == 0) atomicAdd(&xn[x], vv);
        }
        __syncthreads();
    }

    for (int cc = 0; cc < 16; ++cc) {
        for (int it = 0; it < 7; ++it) {
            int x = it * 4 + wave, c = lane;
            const float* sp = pooled2 + ((size_t)(b * C2_ + cc * 64 + c)) * 196;
            float sx = x * 0.5f - 0.25f;
            int ix = (int)floorf(sx);
            float fx = sx - ix;
            int x0 = min(max(ix, 0), 13), x1 = min(max(ix + 1, 0), 13);
            float v = (1.f - fy) * ((1.f - fx) * sp[y0 * 14 + x0] + fx * sp[y0 * 14 + x1])
                    + fy * ((1.f - fx) * sp[y1 * 14 + x0] + fx * sp[y1 * 14 + x1]);
            int col = C1_ + cc * 64 + c;
            size_t off = (size_t)(brow + x) * D_ + col;
            u16 h = f2bf(v);
            Ah[off] = h; Al[off] = f2bf(v - bf2f(h));
            float vv = v * v;
            for (int m = 1; m < 64; m <<= 1) vv += __shfl_xor(vv, m, 64);
            if (lane == 0) atomicAdd(&xn[x], vv);
        }
    }
    __syncthreads();
    if (tid < 28) xnorm[brow + tid] = xn[tid];
}

// ---------------- phase-1: bf16 hi-only GEMM, 128x256 tile, DOUBLE-BUFFERED ----
// One barrier per kt; stage(kt+1) issued right AFTER the barrier so the
// compiler's vmcnt(0)-before-s_barrier drain at iteration kt+1 waits on loads
// that had a full compute-iteration of flight time (m97-structure workaround).
typedef __bf16 bf16x8 __attribute__((ext_vector_type(8)));
typedef float  f32x16 __attribute__((ext_vector_type(16)));

#define GLD16(dst, src) __builtin_amdgcn_global_load_lds( \
    (const __attribute__((address_space(1))) void*)(src), \
    (__attribute__((address_space(3))) void*)(dst), 16, 0, 0)

__global__ __launch_bounds__(256, 2)
void k_gemm1(const u16* __restrict__ Ah, const u16* __restrict__ Bh,
             const float* __restrict__ ynorm, float* __restrict__ partf) {
    __shared__ u16 sA[2][128 * 32];    // 16 KB
    __shared__ u16 sB[2][256 * 32];    // 32 KB
    __shared__ float smin[128][2];

    const int tid = threadIdx.x, lane = tid & 63, wave = tid >> 6;
    const int GM = 4, nig = GM * NT_;
    const int grp = blockIdx.x / nig, rem = blockIdx.x - grp * nig;
    const int first = grp * GM;
    const int gsz = (MT2_ - first) < GM ? (MT2_ - first) : GM;
    const int mt = first + rem % gsz;
    const int pt = rem / gsz;
    const int p0 = pt * 128, m0 = mt * 256;

    f32x16 acc[2][4];
#pragma unroll
    for (int i = 0; i < 2; ++i)
#pragma unroll
        for (int j = 0; j < 4; ++j)
#pragma unroll
            for (int e = 0; e < 16; ++e) acc[i][j][e] = 0.f;

    const int srow = lane >> 2;
    const int schunk8 = ((lane & 3) ^ ((lane >> 3) & 3)) * 8;
    const int wr = (wave >> 1) * 64, wc = (wave & 1) * 128;
    const int rA = lane & 31, kh = lane >> 5;
    const int rsw = (lane >> 1) & 3;

    // wave-fixed staging source rows
    const int arow0 = (wave * 2 + 0) * 16 + srow, arow1 = (wave * 2 + 1) * 16 + srow;
    const u16* gA0 = Ah + (size_t)(p0 + arow0) * D_ + schunk8;
    const u16* gA1 = Ah + (size_t)(p0 + arow1) * D_ + schunk8;
    const u16* gB0 = Bh + (size_t)(m0 + (wave * 4 + 0) * 16 + srow) * D_ + schunk8;
    const u16* gB1 = Bh + (size_t)(m0 + (wave * 4 + 1) * 16 + srow) * D_ + schunk8;
    const u16* gB2 = Bh + (size_t)(m0 + (wave * 4 + 2) * 16 + srow) * D_ + schunk8;
    const u16* gB3 = Bh + (size_t)(m0 + (wave * 4 + 3) * 16 + srow) * D_ + schunk8;
    u16* lA0 = &sA[0][(wave * 2 + 0) * 512]; u16* lA1 = &sA[0][(wave * 2 + 1) * 512];
    u16* lB0 = &sB[0][(wave * 4 + 0) * 512]; u16* lB1 = &sB[0][(wave * 4 + 1) * 512];
    u16* lB2 = &sB[0][(wave * 4 + 2) * 512]; u16* lB3 = &sB[0][(wave * 4 + 3) * 512];
    const size_t bufA = 128 * 32, bufB = 256 * 32;   // u16 elems per buffer

    // prologue: stage kt=0 into buffer 0
    GLD16(lA0, gA0); GLD16(lA1, gA1);
    GLD16(lB0, gB0); GLD16(lB1, gB1); GLD16(lB2, gB2); GLD16(lB3, gB3);

    for (int kt = 0; kt < 48; ++kt) {
        const int cur = kt & 1, nxt = cur ^ 1;
        __syncthreads();   // drains stage(kt) (issued one iteration ago)
        if (kt < 47) {
            const int k1 = (kt + 1) * 32;
            GLD16(lA0 + nxt * bufA, gA0 + k1); GLD16(lA1 + nxt * bufA, gA1 + k1);
            GLD16(lB0 + nxt * bufB, gB0 + k1); GLD16(lB1 + nxt * bufB, gB1 + k1);
            GLD16(lB2 + nxt * bufB, gB2 + k1); GLD16(lB3 + nxt * bufB, gB3 + k1);
        }
        bf16x8 af[2][2], bfr[2][4];
#pragma unroll
        for (int ks = 0; ks < 2; ++ks) {
            const int slot = ((ks * 2 + kh) ^ rsw) * 8;
#pragma unroll
            for (int ti = 0; ti < 2; ++ti)
                af[ks][ti] = *(const bf16x8*)&sA[cur][(wr + ti * 32 + rA) * 32 + slot];
#pragma unroll
            for (int tj = 0; tj < 4; ++tj)
                bfr[ks][tj] = *(const bf16x8*)&sB[cur][(wc + tj * 32 + rA) * 32 + slot];
        }
#pragma unroll
        for (int ks = 0; ks < 2; ++ks)
#pragma unroll
            for (int ti = 0; ti < 2; ++ti)
#pragma unroll
                for (int tj = 0; tj < 4; ++tj)
                    acc[ti][tj] = __builtin_amdgcn_mfma_f32_32x32x16_bf16(
                        af[ks][ti], bfr[ks][tj], acc[ti][tj], 0, 0, 0);
    }

    // epilogue: C layout (32x32): col = lane&31, row = (reg&3)+8*(reg>>2)+4*kh
    const int c32 = lane & 31;
    float yn[4];
#pragma unroll
    for (int tj = 0; tj < 4; ++tj) yn[tj] = ynorm[m0 + wc + tj * 32 + c32];
#pragma unroll
    for (int ti = 0; ti < 2; ++ti) {
#pragma unroll
        for (int reg = 0; reg < 16; ++reg) {
            const int rloc = wr + ti * 32 + (reg & 3) + 8 * (reg >> 2) + 4 * kh;
            float v = __uint_as_float(0x7f800000u);
#pragma unroll
            for (int tj = 0; tj < 4; ++tj)
                v = fminf(v, yn[tj] - 2.0f * acc[ti][tj][reg]);
#pragma unroll
            for (int msk = 1; msk < 32; msk <<= 1)
                v = fminf(v, __shfl_xor(v, msk, 64));
            if (c32 == 0) smin[rloc][wave & 1] = v;
        }
    }
    __syncthreads();
    if (tid < 128)
        partf[(size_t)mt * N_ + p0 + tid] = fminf(smin[tid][0], smin[tid][1]);
}

// ---------------- reduce partial mins -> approx patch scores ----------------
__global__ void k_reduce(const float* __restrict__ partf, const float* __restrict__ xnorm,
                         float* __restrict__ ps) {
    int n = blockIdx.x * 128 + threadIdx.x;
    float best = __uint_as_float(0x7f800000u);
    for (int t = 0; t < MT2_; ++t)
        best = fminf(best, partf[(size_t)t * N_ + n]);
    ps[n] = sqrtf(fmaxf(best + xnorm[n], 0.f));
}

// ---------------- per-image approx top-8 patches (candidates) ----------------
__global__ void k_cand(const float* __restrict__ ps, int* __restrict__ candrow) {
    int b = blockIdx.x, tid = threadIdx.x;
    __shared__ u64 red[4];
    u64 prev = ~0ull;
    for (int j = 0; j < 8; ++j) {
        u64 best = 0;
        for (int p = tid; p < P_; p += 256) {
            u64 pk = ((u64)ordf(ps[b * P_ + p]) << 32) | (u32)(~(u32)p);
            if (pk < prev && pk > best) best = pk;
        }
        for (int msk = 1; msk < 64; msk <<= 1) {
            u64 o = __shfl_xor(best, msk, 64);
            best = o > best ? o : best;
        }
        int wave = tid >> 6, lane = tid & 63;
        if (lane == 0) red[wave] = best;
        __syncthreads();
        u64 m = red[0];
        for (int w = 1; w < 4; ++w) m = red[w] > m ? red[w] : m;
        if (tid == 0) candrow[b * 8 + j] = b * P_ + (int)(~(u32)m);
        prev = m;
        __syncthreads();
    }
}

// ---------------- phase-2: exact 3-term split GEMM, SPLIT-K x4 ----------------
// grid (118, 4): block (mt, slice) computes partial dot over K-chunk of 384,
// writes raw sums to pdot[slice][mt][cand][mlocal]. k_pickc reduces.
__global__ __launch_bounds__(256)
void k_gexact(const u16* __restrict__ Ah, const u16* __restrict__ Al,
              const u16* __restrict__ Bh, const u16* __restrict__ Bl,
              const int* __restrict__ candrow, float* __restrict__ pdot) {
    __shared__ u16 sA[2][128 * 32];
    __shared__ u16 sB[2][128 * 32];
    __shared__ int scand[128];

    const int tid = threadIdx.x;
    const int lane = tid & 63, wave = tid >> 6;
    const int mt = blockIdx.x, slice = blockIdx.y;
    const int m0 = mt * 128;
    if (tid < 128) scand[tid] = candrow[tid];

    f32x16 acc[2][2];
#pragma unroll
    for (int i = 0; i < 2; ++i)
#pragma unroll
        for (int j = 0; j < 2; ++j)
#pragma unroll
            for (int e = 0; e < 16; ++e) acc[i][j][e] = 0.f;

    const int srow = lane >> 2;
    const int scol = ((lane & 3) ^ ((lane >> 3) & 3)) * 8;
    const int wr = (wave >> 1) * 64, wc = (wave & 1) * 64;
    const int rA = lane & 31;
    const int sw = (lane >> 1) & 3;
    __syncthreads();

    for (int kt = slice * 12; kt < slice * 12 + 12; ++kt) {
        const int k0 = kt * 32;
#pragma unroll
        for (int s = 0; s < 2; ++s) {
            const int slab = wave * 2 + s;
            const int row = slab * 16 + srow;
            const int grow = scand[row];
            GLD16(&sA[0][slab * 512], Ah + (size_t)grow * D_ + k0 + scol);
            GLD16(&sA[1][slab * 512], Al + (size_t)grow * D_ + k0 + scol);
            GLD16(&sB[0][slab * 512], Bh + (size_t)(m0 + row) * D_ + k0 + scol);
            GLD16(&sB[1][slab * 512], Bl + (size_t)(m0 + row) * D_ + k0 + scol);
        }
        __syncthreads();
#pragma unroll
        for (int ks = 0; ks < 2; ++ks) {
            const int co = ((ks * 2 + (lane >> 5)) ^ sw) * 8;
            bf16x8 ah0 = *(const bf16x8*)&sA[0][(wr + rA) * 32 + co];
            bf16x8 ah1 = *(const bf16x8*)&sA[0][(wr + 32 + rA) * 32 + co];
            bf16x8 al0 = *(const bf16x8*)&sA[1][(wr + rA) * 32 + co];
            bf16x8 al1 = *(const bf16x8*)&sA[1][(wr + 32 + rA) * 32 + co];
            bf16x8 bh0 = *(const bf16x8*)&sB[0][(wc + rA) * 32 + co];
            bf16x8 bh1 = *(const bf16x8*)&sB[0][(wc + 32 + rA) * 32 + co];
            bf16x8 bl0 = *(const bf16x8*)&sB[1][(wc + rA) * 32 + co];
            bf16x8 bl1 = *(const bf16x8*)&sB[1][(wc + 32 + rA) * 32 + co];
            acc[0][0] = __builtin_amdgcn_mfma_f32_32x32x16_bf16(ah0, bh0, acc[0][0], 0, 0, 0);
            acc[0][1] = __builtin_amdgcn_mfma_f32_32x32x16_bf16(ah0, bh1, acc[0][1], 0, 0, 0);
            acc[1][0] = __builtin_amdgcn_mfma_f32_32x32x16_bf16(ah1, bh0, acc[1][0], 0, 0, 0);
            acc[1][1] = __builtin_amdgcn_mfma_f32_32x32x16_bf16(ah1, bh1, acc[1][1], 0, 0, 0);
            acc[0][0] = __builtin_amdgcn_mfma_f32_32x32x16_bf16(ah0, bl0, acc[0][0], 0, 0, 0);
            acc[0][1] = __builtin_amdgcn_mfma_f32_32x32x16_bf16(ah0, bl1, acc[0][1], 0, 0, 0);
            acc[1][0] = __builtin_amdgcn_mfma_f32_32x32x16_bf16(ah1, bl0, acc[1][0], 0, 0, 0);
            acc[1][1] = __builtin_amdgcn_mfma_f32_32x32x16_bf16(ah1, bl1, acc[1][1], 0, 0, 0);
            acc[0][0] = __builtin_amdgcn_mfma_f32_32x32x16_bf16(al0, bh0, acc[0][0], 0, 0, 0);
            acc[0][1] = __builtin_amdgcn_mfma_f32_32x32x16_bf16(al0, bh1, acc[0][1], 0, 0, 0);
            acc[1][0] = __builtin_amdgcn_mfma_f32_32x32x16_bf16(al1, bh0, acc[1][0], 0, 0, 0);
            acc[1][1] = __builtin_amdgcn_mfma_f32_32x32x16_bf16(al1, bh1, acc[1][1], 0, 0, 0);
        }
        __syncthreads();
    }

    // write raw partial dots (C layout 32x32: col=lane&31, row=(reg&3)+8*(reg>>2)+4*half)
    const int wrB = wave >> 1, wcB = wave & 1;
    const int half = lane >> 5, c32 = lane & 31;
    float* base = pdot + ((size_t)(slice * MT1_ + mt) * 128) * 128;
#pragma unroll
    for (int ti = 0; ti < 2; ++ti) {
#pragma unroll
        for (int reg = 0; reg < 16; ++reg) {
            const int rloc = wrB * 64 + ti * 32 + 4 * half + (reg & 3) + 8 * (reg >> 2);
#pragma unroll
            for (int tj = 0; tj < 2; ++tj)
                base[(size_t)rloc * 128 + wcB * 64 + tj * 32 + c32] = acc[ti][tj][reg];
        }
    }
}

// ---------------- per-candidate exact min over all m ----------------
__global__ void k_pickc(const float* __restrict__ pdot, const float* __restrict__ ynorm,
                        u64* __restrict__ candmin) {
    int i = blockIdx.x, tid = threadIdx.x;   // cand index 0..127
    __shared__ u64 red[4];
    u64 best = ~0ull;
    for (int m = tid; m < MPAD_; m += 256) {
        float dot = 0.f;
#pragma unroll
        for (int s = 0; s < 4; ++s)
            dot += pdot[((size_t)(s * MT1_ + (m >> 7)) * 128 + i) * 128 + (m & 127)];
        float v = ynorm[m] - 2.f * dot;
        u64 pk = ((u64)ordf(v) << 32) | (u32)m;
        best = pk < best ? pk : best;
    }
    for (int msk = 1; msk < 64; msk <<= 1) {
        u64 o = __shfl_xor(best, msk, 64);
        best = o < best ? o : best;
    }
    int wave = tid >> 6, lane = tid & 63;
    if (lane == 0) red[wave] = best;
    __syncthreads();
    if (tid == 0) {
        u64 m = red[0];
        for (int w = 1; w < 4; ++w) m = red[w] < m ? red[w] : m;
        candmin[i] = m;
    }
}

// ---------------- pick exact winner per image ----------------
__global__ void k_pick(const u64* __restrict__ candmin, const float* __restrict__ xnorm,
                       const int* __restrict__ candrow, int* __restrict__ mprow,
                       int* __restrict__ nnidx, float* __restrict__ score) {
    __shared__ float sps[128];
    __shared__ int sloc[128];
    int i = threadIdx.x;   // 0..127
    u64 best = candmin[i];
    float val = unordf((u32)(best >> 32)) + xnorm[candrow[i]];
    sps[i] = sqrtf(fmaxf(val, 0.f));
    sloc[i] = (int)(u32)best;
    __syncthreads();
    if (i < B_) {
        float bs = -1.f; int bj = 0; int brw = 1 << 30;
        for (int j = 0; j < 8; ++j) {
            int idx = i * 8 + j;
            float v = sps[idx];
            int row = candrow[idx];
            if (v > bs || (v == bs && row < brw)) { bs = v; bj = idx; brw = row; }
        }
        mprow[i] = brw;
        nnidx[i] = sloc[bj];
        score[i] = bs;
    }
}

// ---------------- d_nb: dist(bank[nn_index[b]], bank) exact fp32 ----------------
__global__ void k_dnb(const float* __restrict__ bank, const float* __restrict__ ynorm,
                      const int* __restrict__ nnidx, float* __restrict__ dnb) {
    int wave = threadIdx.x >> 6, lane = threadIdx.x & 63;
    int m = blockIdx.x * 4 + wave;
    if (m >= M_) return;
    const float4* br = (const float4*)(bank + (size_t)m * D_);
    float acc[B_];
#pragma unroll
    for (int b = 0; b < B_; ++b) acc[b] = 0.f;
#pragma unroll
    for (int p = 0; p < 6; ++p) {
        float4 c = br[p * 64 + lane];
#pragma unroll
        for (int b = 0; b < B_; ++b) {
            const float4* nr = (const float4*)(bank + (size_t)nnidx[b] * D_);
            float4 a = nr[p * 64 + lane];
            acc[b] += a.x * c.x + a.y * c.y + a.z * c.z + a.w * c.w;
        }
    }
    float ym = ynorm[m];
    float keep = 0.f;
#pragma unroll
    for (int b = 0; b < B_; ++b) {
        float v = acc[b];
        for (int msk = 1; msk < 64; msk <<= 1) v += __shfl_xor(v, msk, 64);
        if (lane == b) keep = v;
    }
    if (lane < B_) {
        float ynn = ynorm[nnidx[lane]];
        dnb[lane * M_ + m] = sqrtf(fmaxf(ynn - 2.f * keep + ym, 0.f));
    }
}

// ---------------- top-9 smallest of dnb, two-stage exact ----------------
__global__ void k_top9a(const float* __restrict__ dnb, u64* __restrict__ cand9) {
    int blk = blockIdx.x;            // b*8 + chunk
    int b = blk >> 3, ch = blk & 7;
    int base = ch * 1875;
    int tid = threadIdx.x;
    __shared__ u64 red[4];
    u64 prev = 0;
    for (int p = 0; p < 9; ++p) {
        u64 best = ~0ull;
        for (int i = tid; i < 1875; i += 256) {
            float v = dnb[b * M_ + base + i];
            u64 pk = ((u64)ordf(v) << 32) | (u32)(base + i);
            if (pk > prev && pk < best) best = pk;
        }
        for (int msk = 1; msk < 64; msk <<= 1) {
            u64 o = __shfl_xor(best, msk, 64);
            best = o < best ? o : best;
        }
        int wave = tid >> 6, lane = tid & 63;
        if (lane == 0) red[wave] = best;
        __syncthreads();
        u64 m = red[0];
        for (int w = 1; w < 4; ++w) m = red[w] < m ? red[w] : m;
        if (tid == 0) cand9[blk * 9 + p] = m;
        prev = m;
        __syncthreads();
    }
}
__global__ void k_top9b(const u64* __restrict__ cand9, int* __restrict__ support) {
    int b = blockIdx.x, lane = threadIdx.x;   // 64 threads
    u64 v0 = lane < 72 ? cand9[b * 72 + lane] : ~0ull;
    u64 v1 = (lane + 64) < 72 ? cand9[b * 72 + lane + 64] : ~0ull;
    u64 prev = 0;
    for (int p = 0; p < 9; ++p) {
        u64 best = ~0ull;
        if (v0 > prev && v0 < best) best = v0;
        if (v1 > prev && v1 < best) best = v1;
        for (int msk = 1; msk < 64; msk <<= 1) {
            u64 o = __shfl_xor(best, msk, 64);
            best = o < best ? o : best;
        }
        if (lane == 0) support[b * 9 + p] = (int)(u32)best;
        prev = best;
    }
}

// ---------------- d2 + softmax reweight -> pred_score ----------------
__global__ void k_final(const u16* __restrict__ Ah, const u16* __restrict__ Al,
                        const float* __restrict__ bank, const float* __restrict__ ynorm,
                        const float* __restrict__ xnorm, const int* __restrict__ mprow,
                        const int* __restrict__ support, const float* __restrict__ score,
                        float* __restrict__ out_score) {
    int b = blockIdx.x;
    int wave = threadIdx.x >> 6, lane = threadIdx.x & 63;
    __shared__ float d2s[9];
    int row = mprow[b];
    float xn = xnorm[row];
    for (int s = wave; s < 9; s += 4) {
        int sup = support[b * 9 + s];
        float acc = 0.f;
        for (int p = 0; p < 24; ++p) {
            int k = p * 64 + lane;
            float e = bf2f(Ah[(size_t)row * D_ + k]) + bf2f(Al[(size_t)row * D_ + k]);
            acc += e * bank[(size_t)sup * D_ + k];
        }
        for (int msk = 1; msk < 64; msk <<= 1) acc += __shfl_xor(acc, msk, 64);
        if (lane == 0) d2s[s] = sqrtf(fmaxf(xn - 2.f * acc + ynorm[sup], 0.f));
    }
    __syncthreads();
    if (threadIdx.x == 0) {
        float mx = d2s[0];
        for (int i = 1; i < 9; ++i) mx = fmaxf(mx, d2s[i]);
        float den = 0.f;
        for (int i = 0; i < 9; ++i) den += expf(d2s[i] - mx);
        float w = 1.f - expf(d2s[0] - mx) / den;
        out_score[b] = w * score[b];
    }
}

// ---------------- bilinear upsample 28->224 ----------------
__global__ void k_upsample(const float* __restrict__ ps, float* __restrict__ U) {
    int idx = blockIdx.x * 256 + threadIdx.x;
    if (idx >= B_ * IMG_ * IMG_) return;
    int x = idx % IMG_, y = (idx / IMG_) % IMG_, b = idx / (IMG_ * IMG_);
    float sx = x * 0.125f - 0.4375f, sy = y * 0.125f - 0.4375f;
    int ix = (int)floorf(sx), iy = (int)floorf(sy);
    float fx = sx - ix, fy = sy - iy;
    int x0 = min(max(ix, 0), 27), x1 = min(max(ix + 1, 0), 27);
    int y0 = min(max(iy, 0), 27), y1 = min(max(iy + 1, 0), 27);
    const float* p = ps + b * P_;
    U[idx] = (1.f - fy) * ((1.f - fx) * p[y0 * 28 + x0] + fx * p[y0 * 28 + x1])
           + fy * ((1.f - fx) * p[y1 * 28 + x0] + fx * p[y1 * 28 + x1]);
}

// ---------------- separable gaussian blur, reflect pad ----------------
__global__ void k_blurh(const float* __restrict__ U, float* __restrict__ T) {
    __shared__ float g[KS_];
    __shared__ float gs;
    int tid = threadIdx.x;
    if (tid < KS_) { float d = tid - 16.f; g[tid] = expf(-(d * d) / 32.0f); }
    __syncthreads();
    if (tid == 0) { float s = 0.f; for (int i = 0; i < KS_; ++i) s += g[i]; gs = 1.f / s; }
    __syncthreads();
    int idx = blockIdx.x * 256 + tid;
    if (idx >= B_ * IMG_ * IMG_) return;
    int x = idx % IMG_, rowbase = idx - x;
    float a = 0.f;
    for (int t = 0; t < KS_; ++t) {
        int xx = x + t - 16;
        xx = xx < 0 ? -xx : (xx > 223 ? 446 - xx : xx);
        a += g[t] * U[rowbase + xx];
    }
    T[idx] = a * gs;
}
__global__ void k_blurv(const float* __restrict__ T, float* __restrict__ out) {
    __shared__ float g[KS_];
    __shared__ float gs;
    int tid = threadIdx.x;
    if (tid < KS_) { float d = tid - 16.f; g[tid] = expf(-(d * d) / 32.0f); }
    __syncthreads();
    if (tid == 0) { float s = 0.f; for (int i = 0; i < KS_; ++i) s += g[i]; gs = 1.f / s; }
    __syncthreads();
    int idx = blockIdx.x * 256 + tid;
    if (idx >= B_ * IMG_ * IMG_) return;
    int x = idx % IMG_, y = (idx / IMG_) % IMG_, b = idx / (IMG_ * IMG_);
    float a = 0.f;
    for (int t = 0; t < KS_; ++t) {
        int yy = y + t - 16;
        yy = yy < 0 ? -yy : (yy > 223 ? 446 - yy : yy);
        a += g[t] * T[(b * IMG_ + yy) * IMG_ + x];
    }
    out[idx] = a * gs;
}

// ---------------- launch ----------------
extern "C" void kernel_launch(void* const* d_in, const int* in_sizes, int n_in,
                              void* d_out, int out_size, void* d_ws, size_t ws_size,
                              hipStream_t stream) {
    const float* feat1 = (const float*)d_in[0];
    const float* feat2 = (const float*)d_in[1];
    const float* bank  = (const float*)d_in[2];
    float* out = (float*)d_out;
    char* ws = (char*)d_ws;

    size_t o = 0;
    u16* Ah = (u16*)(ws + o); o += (size_t)N_ * D_ * 2;
    u16* Al = (u16*)(ws + o); o += (size_t)N_ * D_ * 2;
    size_t o_Bh = o;
    u16* Bh = (u16*)(ws + o); o += (size_t)MPAD_ * D_ * 2;
    u16* Bl = (u16*)(ws + o); o += (size_t)MPAD_ * D_ * 2;
    // scratch union: pooled2 (pre-GEMM) / partf (GEMM phase)
    size_t o_scr = o;
    float* pooled2 = (float*)(ws + o_scr);
    float* partf   = (float*)(ws + o_scr);
    size_t r1 = (size_t)MT2_ * N_ * 4, r2 = (size_t)B_ * C2_ * 196 * 4;
    o += (r1 > r2 ? r1 : r2);
    float* xnorm = (float*)(ws + o); o += (size_t)N_ * 4;
    float* ynorm = (float*)(ws + o); o += (size_t)MPAD_ * 4;
    float* ps    = (float*)(ws + o); o += (size_t)N_ * 4;
    int* candrow = (int*)(ws + o);   o += 512;
    float* pdot  = (float*)(ws + o); o += (size_t)4 * MT1_ * 128 * 128 * 4;
    u64* candmin = (u64*)(ws + o);   o += 128 * 8;
    float* dnb   = (float*)(ws + o); o += (size_t)B_ * M_ * 4;
    u64* cand9   = (u64*)(ws + o);   o += 128 * 9 * 8;
    int*   mprow = (int*)(ws + o);   o += 64;
    int*   nnidx = (int*)(ws + o);   o += 64;
    float* score = (float*)(ws + o); o += 64;
    int* support = (int*)(ws + o);   o += 9 * B_ * 4;
    // U/T alias the Bh/Bl region (dead after k_gexact)
    float* U = (float*)(ws + o_Bh);
    float* T = (float*)(ws + o_Bh + (size_t)B_ * IMG_ * IMG_ * 4);

    k_pool2<<<(B_ * C2_ * H2_ * H2_ + 255) / 256, 256, 0, stream>>>(feat2, pooled2);
    k_bank<<<MPAD_, 192, 0, stream>>>(bank, Bh, Bl, ynorm);
    k_embed<<<B_ * 28, 256, 0, stream>>>(feat1, pooled2, Ah, Al, xnorm);
    k_gemm1<<<MT2_ * NT_, 256, 0, stream>>>(Ah, Bh, ynorm, partf);
    k_reduce<<<NT_, 128, 0, stream>>>(partf, xnorm, ps);
    k_cand<<<B_, 256, 0, stream>>>(ps, candrow);
    k_gexact<<<dim3(MT1_, 4), 256, 0, stream>>>(Ah, Al, Bh, Bl, candrow, pdot);
    k_pickc<<<128, 256, 0, stream>>>(pdot, ynorm, candmin);
    k_pick<<<1, 128, 0, stream>>>(candmin, xnorm, candrow, mprow, nnidx, score);
    k_dnb<<<(M_ + 3) / 4, 256, 0, stream>>>(bank, ynorm, nnidx, dnb);
    k_top9a<<<128, 256, 0, stream>>>(dnb, cand9);
    k_top9b<<<B_, 64, 0, stream>>>(cand9, support);
    k_final<<<B_, 256, 0, stream>>>(Ah, Al, bank, ynorm, xnorm, mprow, support, score,
                                    out + (size_t)B_ * IMG_ * IMG_);
    k_upsample<<<(B_ * IMG_ * IMG_ + 255) / 256, 256, 0, stream>>>(ps, U);
    k_blurh<<<(B_ * IMG_ * IMG_ + 255) / 256, 256, 0, stream>>>(U, T);
    k_blurv<<<(B_ * IMG_ * IMG_ + 255) / 256, 256, 0, stream>>>(T, out);
}

// Round 7
// 1253.252 us; speedup vs baseline: 1.0548x; 1.0548x over previous
//
#include <hip/hip_runtime.h>
#include <stdint.h>

// ---------------- problem constants ----------------
#define B_    16
#define C1_   512
#define C2_   1024
#define H2_   14
#define D_    1536
#define K16_  96           // D / 16
#define P_    784          // 28*28
#define N_    12544        // B_*P_
#define M_    15000
#define MPAD_ 15104        // 59*256 padded bank rows
#define MT1_  118          // 128-wide m tiles (k_gexact)
#define MT2_  59           // 256-wide m tiles (k_gemm1)
#define NT_   98           // patch tiles of 128
#define IMG_  224
#define KS_   33

typedef unsigned short u16;
typedef unsigned int   u32;
typedef unsigned long long u64;

// ---------------- helpers ----------------
__device__ __forceinline__ u16 f2bf(float x) {
    u32 u = __float_as_uint(x);
    u = u + 0x7fffu + ((u >> 16) & 1u);   // RNE
    return (u16)(u >> 16);
}
__device__ __forceinline__ float bf2f(u16 h) {
    return __uint_as_float(((u32)h) << 16);
}
__device__ __forceinline__ u32 ordf(float f) {
    u32 u = __float_as_uint(f);
    return (u & 0x80000000u) ? ~u : (u | 0x80000000u);
}
__device__ __forceinline__ float unordf(u32 o) {
    u32 u = (o & 0x80000000u) ? (o ^ 0x80000000u) : ~o;
    return __uint_as_float(u);
}

// Fragment-packed layouts (32x32x16 bf16 A/B operand order):
//   lane = kh*32 + r32  (kh = which 8-of-16 k, r32 = row/col within 32-group)
//   Apack[pt][k16][g:4][lane:64][j:8]   (128-row patch tiles)
//   Bpack[mt][k16][gb:8][lane:64][j:8]  (256-row bank tiles)
// Every MFMA fragment = one coalesced 16B/lane load (1 KB/wave). No LDS.

// ---------------- avg-pool feat2 -> pooled2 [16,1024,14,14] ----------------
__global__ void k_pool2(const float* __restrict__ feat2, float* __restrict__ pooled2) {
    int idx = blockIdx.x * 256 + threadIdx.x;
    if (idx >= B_ * C2_ * H2_ * H2_) return;
    int x = idx % 14, y = (idx / 14) % 14, bc = idx / 196;
    const float* src = feat2 + (size_t)bc * 196;
    float s = 0.f;
    for (int dy = -1; dy <= 1; ++dy) {
        int yy = y + dy; if (yy < 0 || yy > 13) continue;
        for (int dx = -1; dx <= 1; ++dx) {
            int xx = x + dx; if (xx < 0 || xx > 13) continue;
            s += src[yy * 14 + xx];
        }
    }
    pooled2[idx] = s * (1.f / 9.f);
}

// ---------------- bank split -> fragment-packed hi/lo + norms ----------------
__global__ __launch_bounds__(192)
void k_bank(const float* __restrict__ bank, u16* __restrict__ Bph,
            u16* __restrict__ Bpl, float* __restrict__ ynorm) {
    int m = blockIdx.x, tid = threadIdx.x;
    float nrm = 0.f;
    float v[8];
    if (m < M_) {
        const float4* src = (const float4*)(bank + (size_t)m * D_ + tid * 8);
        float4 a = src[0], b = src[1];
        v[0]=a.x; v[1]=a.y; v[2]=a.z; v[3]=a.w; v[4]=b.x; v[5]=b.y; v[6]=b.z; v[7]=b.w;
#pragma unroll
        for (int i = 0; i < 8; ++i) nrm += v[i] * v[i];
    } else {
#pragma unroll
        for (int i = 0; i < 8; ++i) v[i] = 0.f;
    }
    u32 hw[4], lw[4];
#pragma unroll
    for (int i = 0; i < 4; ++i) {
        u16 h0 = f2bf(v[2*i]),   l0 = f2bf(v[2*i]   - bf2f(h0));
        u16 h1 = f2bf(v[2*i+1]), l1 = f2bf(v[2*i+1] - bf2f(h1));
        hw[i] = (u32)h0 | ((u32)h1 << 16);
        lw[i] = (u32)l0 | ((u32)l1 << 16);
    }
    // packed offset: c = tid*8 .. +7 (single k16, single kh)
    int c = tid * 8;
    int k16 = c >> 4, kh = (c >> 3) & 1;
    int mt2 = m >> 8, r = m & 255, gb = r >> 5, rA = r & 31;
    size_t off = ((((size_t)mt2 * K16_ + k16) * 8 + gb) * 64 + kh * 32 + rA) * 8;
    *(uint4*)(Bph + off) = make_uint4(hw[0], hw[1], hw[2], hw[3]);
    *(uint4*)(Bpl + off) = make_uint4(lw[0], lw[1], lw[2], lw[3]);
    __shared__ float red[3];
    for (int offr = 32; offr; offr >>= 1) nrm += __shfl_down(nrm, offr, 64);
    int wave = tid >> 6, lane = tid & 63;
    if (lane == 0) red[wave] = nrm;
    __syncthreads();
    if (tid == 0) {
        float t = red[0] + red[1] + red[2];
        ynorm[m] = (m < M_) ? t : __uint_as_float(0x7f800000u);  // +inf pad
    }
}

// ---------------- embedding build -> row-major Ah/Al + fragment-packed Aph ----
__device__ __forceinline__ void emb_store(u16* Ah, u16* Al, u16* Aph,
                                          int n, int col, float v) {
    u16 h = f2bf(v);
    size_t off = (size_t)n * D_ + col;
    Ah[off] = h; Al[off] = f2bf(v - bf2f(h));
    int pt = n >> 7, r = n & 127, g = r >> 5, rA = r & 31;
    int k16 = col >> 4, kh = (col >> 3) & 1, j = col & 7;
    Aph[((((size_t)pt * K16_ + k16) * 4 + g) * 64 + kh * 32 + rA) * 8 + j] = h;
}

__global__ __launch_bounds__(256)
void k_embed(const float* __restrict__ feat1, const float* __restrict__ pooled2,
             u16* __restrict__ Ah, u16* __restrict__ Al, u16* __restrict__ Aph,
             float* __restrict__ xnorm) {
    __shared__ float sF[3 * 64 * 29];   // [r][c][x] padded to 29
    __shared__ float xn[28];
    const int tid = threadIdx.x, lane = tid & 63, wave = tid >> 6;
    const int b = blockIdx.x / 28, y = blockIdx.x % 28;
    const int brow = b * P_ + y * 28;
    if (tid < 28) xn[tid] = 0.f;

    float sy = y * 0.5f - 0.25f;
    int iy = (int)floorf(sy);
    float fy = sy - iy;
    int y0 = min(max(iy, 0), 13), y1 = min(max(iy + 1, 0), 13);
    __syncthreads();

    for (int cc = 0; cc < 8; ++cc) {
        for (int j = tid; j < 3 * 64 * 28; j += 256) {
            int x = j % 28, c = (j / 28) % 64, r = j / (28 * 64);
            int yy = y - 1 + r;
            float v = 0.f;
            if (yy >= 0 && yy < 28)
                v = feat1[((size_t)(b * C1_ + cc * 64 + c)) * 784 + yy * 28 + x];
            sF[(r * 64 + c) * 29 + x] = v;
        }
        __syncthreads();
        for (int it = 0; it < 7; ++it) {
            int x = it * 4 + wave, c = lane;
            float s = 0.f;
#pragma unroll
            for (int r = 0; r < 3; ++r) {
                int base = (r * 64 + c) * 29;
                if (x > 0) s += sF[base + x - 1];
                s += sF[base + x];
                if (x < 27) s += sF[base + x + 1];
            }
            float v = s * (1.f / 9.f);
            emb_store(Ah, Al, Aph, brow + x, cc * 64 + c, v);
            float vv = v * v;
            for (int m = 1; m < 64; m <<= 1) vv += __shfl_xor(vv, m, 64);
            if (lane == 0) atomicAdd(&xn[x], vv);
        }
        __syncthreads();
    }

    for (int cc = 0; cc < 16; ++cc) {
        for (int it = 0; it < 7; ++it) {
            int x = it * 4 + wave, c = lane;
            const float* sp = pooled2 + ((size_t)(b * C2_ + cc * 64 + c)) * 196;
            float sx = x * 0.5f - 0.25f;
            int ix = (int)floorf(sx);
            float fx = sx - ix;
            int x0 = min(max(ix, 0), 13), x1 = min(max(ix + 1, 0), 13);
            float v = (1.f - fy) * ((1.f - fx) * sp[y0 * 14 + x0] + fx * sp[y0 * 14 + x1])
                    + fy * ((1.f - fx) * sp[y1 * 14 + x0] + fx * sp[y1 * 14 + x1]);
            emb_store(Ah, Al, Aph, brow + x, C1_ + cc * 64 + c, v);
            float vv = v * v;
            for (int m = 1; m < 64; m <<= 1) vv += __shfl_xor(vv, m, 64);
            if (lane == 0) atomicAdd(&xn[x], vv);
        }
    }
    __syncthreads();
    if (tid < 28) xnorm[brow + tid] = xn[tid];
}

// ---------------- phase-1: bf16 hi-only GEMM, NO-LDS fragment streaming -------
// 128x256 block, wave = 64x128 (2x4 of 32x32). All fragments loaded directly
// from fragment-packed global (coalesced 16B/lane, L2/L3-served). Barrier-free
// K-loop: compiler pipelines plain VMEM loads with fine-grained vmcnt — the
// structure the LDS path (vmcnt(0) drain before s_barrier) cannot express.
typedef __bf16 bf16x8 __attribute__((ext_vector_type(8)));
typedef float  f32x16 __attribute__((ext_vector_type(16)));

__global__ __launch_bounds__(256, 2)
void k_gemm1(const u16* __restrict__ Aph, const u16* __restrict__ Bph,
             const float* __restrict__ ynorm, float* __restrict__ partf) {
    __shared__ float smin[128][2];
    const int tid = threadIdx.x, lane = tid & 63, wave = tid >> 6;
    const int GM = 4, nig = GM * NT_;
    const int grp = blockIdx.x / nig, rem = blockIdx.x - grp * nig;
    const int first = grp * GM;
    const int gsz = (MT2_ - first) < GM ? (MT2_ - first) : GM;
    const int mt = first + rem % gsz;
    const int pt = rem / gsz;
    const int p0 = pt * 128, m0 = mt * 256;

    f32x16 acc[2][4];
#pragma unroll
    for (int i = 0; i < 2; ++i)
#pragma unroll
        for (int j = 0; j < 4; ++j)
#pragma unroll
            for (int e = 0; e < 16; ++e) acc[i][j][e] = 0.f;

    const int wr = (wave >> 1) * 64, wc = (wave & 1) * 128;
    const u16* aB = Aph + ((size_t)pt * K16_ * 4 + (wr >> 5)) * 512 + lane * 8;
    const u16* bB = Bph + ((size_t)mt * K16_ * 8 + (wc >> 5)) * 512 + lane * 8;

#pragma unroll 4
    for (int k16 = 0; k16 < K16_; ++k16) {
        bf16x8 af[2], bfr[4];
        const u16* ak = aB + (size_t)k16 * 4 * 512;
        const u16* bk = bB + (size_t)k16 * 8 * 512;
        af[0]  = *(const bf16x8*)(ak);
        af[1]  = *(const bf16x8*)(ak + 512);
        bfr[0] = *(const bf16x8*)(bk);
        bfr[1] = *(const bf16x8*)(bk + 512);
        bfr[2] = *(const bf16x8*)(bk + 1024);
        bfr[3] = *(const bf16x8*)(bk + 1536);
#pragma unroll
        for (int ti = 0; ti < 2; ++ti)
#pragma unroll
            for (int tj = 0; tj < 4; ++tj)
                acc[ti][tj] = __builtin_amdgcn_mfma_f32_32x32x16_bf16(
                    af[ti], bfr[tj], acc[ti][tj], 0, 0, 0);
    }

    // epilogue: C layout (32x32): col = lane&31, row = (reg&3)+8*(reg>>2)+4*kh
    const int c32 = lane & 31, kh = lane >> 5;
    float yn[4];
#pragma unroll
    for (int tj = 0; tj < 4; ++tj) yn[tj] = ynorm[m0 + wc + tj * 32 + c32];
#pragma unroll
    for (int ti = 0; ti < 2; ++ti) {
#pragma unroll
        for (int reg = 0; reg < 16; ++reg) {
            const int rloc = wr + ti * 32 + (reg & 3) + 8 * (reg >> 2) + 4 * kh;
            float v = __uint_as_float(0x7f800000u);
#pragma unroll
            for (int tj = 0; tj < 4; ++tj)
                v = fminf(v, yn[tj] - 2.0f * acc[ti][tj][reg]);
#pragma unroll
            for (int msk = 1; msk < 32; msk <<= 1)
                v = fminf(v, __shfl_xor(v, msk, 64));
            if (c32 == 0) smin[rloc][wave & 1] = v;
        }
    }
    __syncthreads();
    if (tid < 128)
        partf[(size_t)mt * N_ + p0 + tid] = fminf(smin[tid][0], smin[tid][1]);
}

// ---------------- reduce partial mins -> approx patch scores ----------------
__global__ void k_reduce(const float* __restrict__ partf, const float* __restrict__ xnorm,
                         float* __restrict__ ps) {
    int n = blockIdx.x * 128 + threadIdx.x;
    float best = __uint_as_float(0x7f800000u);
    for (int t = 0; t < MT2_; ++t)
        best = fminf(best, partf[(size_t)t * N_ + n]);
    ps[n] = sqrtf(fmaxf(best + xnorm[n], 0.f));
}

// ---------------- per-image approx top-8 patches (candidates) ----------------
__global__ void k_cand(const float* __restrict__ ps, int* __restrict__ candrow) {
    int b = blockIdx.x, tid = threadIdx.x;
    __shared__ u64 red[4];
    u64 prev = ~0ull;
    for (int j = 0; j < 8; ++j) {
        u64 best = 0;
        for (int p = tid; p < P_; p += 256) {
            u64 pk = ((u64)ordf(ps[b * P_ + p]) << 32) | (u32)(~(u32)p);
            if (pk < prev && pk > best) best = pk;
        }
        for (int msk = 1; msk < 64; msk <<= 1) {
            u64 o = __shfl_xor(best, msk, 64);
            best = o > best ? o : best;
        }
        int wave = tid >> 6, lane = tid & 63;
        if (lane == 0) red[wave] = best;
        __syncthreads();
        u64 m = red[0];
        for (int w = 1; w < 4; ++w) m = red[w] > m ? red[w] : m;
        if (tid == 0) candrow[b * 8 + j] = b * P_ + (int)(~(u32)m);
        prev = m;
        __syncthreads();
    }
}

// ---------------- phase-2: exact 3-term split GEMM, SPLIT-K x4 ----------------
// A (gathered candidate rows) staged in LDS; B read from fragment-packed
// global (hi+lo). grid (118, 4).
#define GLD16(dst, src) __builtin_amdgcn_global_load_lds( \
    (const __attribute__((address_space(1))) void*)(src), \
    (__attribute__((address_space(3))) void*)(dst), 16, 0, 0)

__global__ __launch_bounds__(256)
void k_gexact(const u16* __restrict__ Ah, const u16* __restrict__ Al,
              const u16* __restrict__ Bph, const u16* __restrict__ Bpl,
              const int* __restrict__ candrow, float* __restrict__ pdot) {
    __shared__ u16 sA[2][128 * 32];
    __shared__ int scand[128];

    const int tid = threadIdx.x;
    const int lane = tid & 63, wave = tid >> 6;
    const int mt = blockIdx.x, slice = blockIdx.y;
    if (tid < 128) scand[tid] = candrow[tid];

    f32x16 acc[2][2];
#pragma unroll
    for (int i = 0; i < 2; ++i)
#pragma unroll
        for (int j = 0; j < 2; ++j)
#pragma unroll
            for (int e = 0; e < 16; ++e) acc[i][j][e] = 0.f;

    const int srow = lane >> 2;
    const int scol = ((lane & 3) ^ ((lane >> 3) & 3)) * 8;
    const int wr = (wave >> 1) * 64, wc = (wave & 1) * 64;
    const int rA = lane & 31;
    const int sw = (lane >> 1) & 3;
    // B fragment-packed base: mt2 = mt>>1, gb = (mt&1)*4 + wc/32 (+tj)
    const size_t bbase = (((size_t)(mt >> 1) * K16_) * 8 + (mt & 1) * 4 + (wc >> 5)) * 512 + lane * 8;
    __syncthreads();

    for (int kt = slice * 12; kt < slice * 12 + 12; ++kt) {
        const int k0 = kt * 32;
#pragma unroll
        for (int s = 0; s < 2; ++s) {
            const int slab = wave * 2 + s;
            const int row = slab * 16 + srow;
            const int grow = scand[row];
            GLD16(&sA[0][slab * 512], Ah + (size_t)grow * D_ + k0 + scol);
            GLD16(&sA[1][slab * 512], Al + (size_t)grow * D_ + k0 + scol);
        }
        __syncthreads();
#pragma unroll
        for (int ks = 0; ks < 2; ++ks) {
            const int co = ((ks * 2 + (lane >> 5)) ^ sw) * 8;
            const size_t bo = bbase + (size_t)(kt * 2 + ks) * 8 * 512;
            bf16x8 ah0 = *(const bf16x8*)&sA[0][(wr + rA) * 32 + co];
            bf16x8 ah1 = *(const bf16x8*)&sA[0][(wr + 32 + rA) * 32 + co];
            bf16x8 al0 = *(const bf16x8*)&sA[1][(wr + rA) * 32 + co];
            bf16x8 al1 = *(const bf16x8*)&sA[1][(wr + 32 + rA) * 32 + co];
            bf16x8 bh0 = *(const bf16x8*)(Bph + bo);
            bf16x8 bh1 = *(const bf16x8*)(Bph + bo + 512);
            bf16x8 bl0 = *(const bf16x8*)(Bpl + bo);
            bf16x8 bl1 = *(const bf16x8*)(Bpl + bo + 512);
            acc[0][0] = __builtin_amdgcn_mfma_f32_32x32x16_bf16(ah0, bh0, acc[0][0], 0, 0, 0);
            acc[0][1] = __builtin_amdgcn_mfma_f32_32x32x16_bf16(ah0, bh1, acc[0][1], 0, 0, 0);
            acc[1][0] = __builtin_amdgcn_mfma_f32_32x32x16_bf16(ah1, bh0, acc[1][0], 0, 0, 0);
            acc[1][1] = __builtin_amdgcn_mfma_f32_32x32x16_bf16(ah1, bh1, acc[1][1], 0, 0, 0);
            acc[0][0] = __builtin_amdgcn_mfma_f32_32x32x16_bf16(ah0, bl0, acc[0][0], 0, 0, 0);
            acc[0][1] = __builtin_amdgcn_mfma_f32_32x32x16_bf16(ah0, bl1, acc[0][1], 0, 0, 0);
            acc[1][0] = __builtin_amdgcn_mfma_f32_32x32x16_bf16(ah1, bl0, acc[1][0], 0, 0, 0);
            acc[1][1] = __builtin_amdgcn_mfma_f32_32x32x16_bf16(ah1, bl1, acc[1][1], 0, 0, 0);
            acc[0][0] = __builtin_amdgcn_mfma_f32_32x32x16_bf16(al0, bh0, acc[0][0], 0, 0, 0);
            acc[0][1] = __builtin_amdgcn_mfma_f32_32x32x16_bf16(al0, bh1, acc[0][1], 0, 0, 0);
            acc[1][0] = __builtin_amdgcn_mfma_f32_32x32x16_bf16(al1, bh0, acc[1][0], 0, 0, 0);
            acc[1][1] = __builtin_amdgcn_mfma_f32_32x32x16_bf16(al1, bh1, acc[1][1], 0, 0, 0);
        }
        __syncthreads();
    }

    // write raw partial dots (C layout 32x32)
    const int wrB = wave >> 1, wcB = wave & 1;
    const int half = lane >> 5, c32 = lane & 31;
    float* base = pdot + ((size_t)(slice * MT1_ + mt) * 128) * 128;
#pragma unroll
    for (int ti = 0; ti < 2; ++ti) {
#pragma unroll
        for (int reg = 0; reg < 16; ++reg) {
            const int rloc = wrB * 64 + ti * 32 + 4 * half + (reg & 3) + 8 * (reg >> 2);
#pragma unroll
            for (int tj = 0; tj < 2; ++tj)
                base[(size_t)rloc * 128 + wcB * 64 + tj * 32 + c32] = acc[ti][tj][reg];
        }
    }
}

// ---------------- per-candidate exact min over all m ----------------
__global__ void k_pickc(const float* __restrict__ pdot, const float* __restrict__ ynorm,
                        u64* __restrict__ candmin) {
    int i = blockIdx.x, tid = threadIdx.x;   // cand index 0..127
    __shared__ u64 red[4];
    u64 best = ~0ull;
    for (int m = tid; m < MPAD_; m += 256) {
        float dot = 0.f;
#pragma unroll
        for (int s = 0; s < 4; ++s)
            dot += pdot[((size_t)(s * MT1_ + (m >> 7)) * 128 + i) * 128 + (m & 127)];
        float v = ynorm[m] - 2.f * dot;
        u64 pk = ((u64)ordf(v) << 32) | (u32)m;
        best = pk < best ? pk : best;
    }
    for (int msk = 1; msk < 64; msk <<= 1) {
        u64 o = __shfl_xor(best, msk, 64);
        best = o < best ? o : best;
    }
    int wave = tid >> 6, lane = tid & 63;
    if (lane == 0) red[wave] = best;
    __syncthreads();
    if (tid == 0) {
        u64 m = red[0];
        for (int w = 1; w < 4; ++w) m = red[w] < m ? red[w] : m;
        candmin[i] = m;
    }
}

// ---------------- pick exact winner per image ----------------
__global__ void k_pick(const u64* __restrict__ candmin, const float* __restrict__ xnorm,
                       const int* __restrict__ candrow, int* __restrict__ mprow,
                       int* __restrict__ nnidx, float* __restrict__ score) {
    __shared__ float sps[128];
    __shared__ int sloc[128];
    int i = threadIdx.x;   // 0..127
    u64 best = candmin[i];
    float val = unordf((u32)(best >> 32)) + xnorm[candrow[i]];
    sps[i] = sqrtf(fmaxf(val, 0.f));
    sloc[i] = (int)(u32)best;
    __syncthreads();
    if (i < B_) {
        float bs = -1.f; int bj = 0; int brw = 1 << 30;
        for (int j = 0; j < 8; ++j) {
            int idx = i * 8 + j;
            float v = sps[idx];
            int row = candrow[idx];
            if (v > bs || (v == bs && row < brw)) { bs = v; bj = idx; brw = row; }
        }
        mprow[i] = brw;
        nnidx[i] = sloc[bj];
        score[i] = bs;
    }
}

// ---------------- d_nb: dist(bank[nn_index[b]], bank) exact fp32 ----------------
__global__ void k_dnb(const float* __restrict__ bank, const float* __restrict__ ynorm,
                      const int* __restrict__ nnidx, float* __restrict__ dnb) {
    int wave = threadIdx.x >> 6, lane = threadIdx.x & 63;
    int m = blockIdx.x * 4 + wave;
    if (m >= M_) return;
    const float4* br = (const float4*)(bank + (size_t)m * D_);
    float acc[B_];
#pragma unroll
    for (int b = 0; b < B_; ++b) acc[b] = 0.f;
#pragma unroll
    for (int p = 0; p < 6; ++p) {
        float4 c = br[p * 64 + lane];
#pragma unroll
        for (int b = 0; b < B_; ++b) {
            const float4* nr = (const float4*)(bank + (size_t)nnidx[b] * D_);
            float4 a = nr[p * 64 + lane];
            acc[b] += a.x * c.x + a.y * c.y + a.z * c.z + a.w * c.w;
        }
    }
    float ym = ynorm[m];
    float keep = 0.f;
#pragma unroll
    for (int b = 0; b < B_; ++b) {
        float v = acc[b];
        for (int msk = 1; msk < 64; msk <<= 1) v += __shfl_xor(v, msk, 64);
        if (lane == b) keep = v;
    }
    if (lane < B_) {
        float ynn = ynorm[nnidx[lane]];
        dnb[lane * M_ + m] = sqrtf(fmaxf(ynn - 2.f * keep + ym, 0.f));
    }
}

// ---------------- top-9 smallest of dnb, two-stage exact ----------------
__global__ void k_top9a(const float* __restrict__ dnb, u64* __restrict__ cand9) {
    int blk = blockIdx.x;            // b*8 + chunk
    int b = blk >> 3, ch = blk & 7;
    int base = ch * 1875;
    int tid = threadIdx.x;
    __shared__ u64 red[4];
    u64 prev = 0;
    for (int p = 0; p < 9; ++p) {
        u64 best = ~0ull;
        for (int i = tid; i < 1875; i += 256) {
            float v = dnb[b * M_ + base + i];
            u64 pk = ((u64)ordf(v) << 32) | (u32)(base + i);
            if (pk > prev && pk < best) best = pk;
        }
        for (int msk = 1; msk < 64; msk <<= 1) {
            u64 o = __shfl_xor(best, msk, 64);
            best = o < best ? o : best;
        }
        int wave = tid >> 6, lane = tid & 63;
        if (lane == 0) red[wave] = best;
        __syncthreads();
        u64 m = red[0];
        for (int w = 1; w < 4; ++w) m = red[w] < m ? red[w] : m;
        if (tid == 0) cand9[blk * 9 + p] = m;
        prev = m;
        __syncthreads();
    }
}
__global__ void k_top9b(const u64* __restrict__ cand9, int* __restrict__ support) {
    int b = blockIdx.x, lane = threadIdx.x;   // 64 threads
    u64 v0 = lane < 72 ? cand9[b * 72 + lane] : ~0ull;
    u64 v1 = (lane + 64) < 72 ? cand9[b * 72 + lane + 64] : ~0ull;
    u64 prev = 0;
    for (int p = 0; p < 9; ++p) {
        u64 best = ~0ull;
        if (v0 > prev && v0 < best) best = v0;
        if (v1 > prev && v1 < best) best = v1;
        for (int msk = 1; msk < 64; msk <<= 1) {
            u64 o = __shfl_xor(best, msk, 64);
            best = o < best ? o : best;
        }
        if (lane == 0) support[b * 9 + p] = (int)(u32)best;
        prev = best;
    }
}

// ---------------- d2 + softmax reweight -> pred_score ----------------
__global__ void k_final(const u16* __restrict__ Ah, const u16* __restrict__ Al,
                        const float* __restrict__ bank, const float* __restrict__ ynorm,
                        const float* __restrict__ xnorm, const int* __restrict__ mprow,
                        const int* __restrict__ support, const float* __restrict__ score,
                        float* __restrict__ out_score) {
    int b = blockIdx.x;
    int wave = threadIdx.x >> 6, lane = threadIdx.x & 63;
    __shared__ float d2s[9];
    int row = mprow[b];
    float xn = xnorm[row];
    for (int s = wave; s < 9; s += 4) {
        int sup = support[b * 9 + s];
        float acc = 0.f;
        for (int p = 0; p < 24; ++p) {
            int k = p * 64 + lane;
            float e = bf2f(Ah[(size_t)row * D_ + k]) + bf2f(Al[(size_t)row * D_ + k]);
            acc += e * bank[(size_t)sup * D_ + k];
        }
        for (int msk = 1; msk < 64; msk <<= 1) acc += __shfl_xor(acc, msk, 64);
        if (lane == 0) d2s[s] = sqrtf(fmaxf(xn - 2.f * acc + ynorm[sup], 0.f));
    }
    __syncthreads();
    if (threadIdx.x == 0) {
        float mx = d2s[0];
        for (int i = 1; i < 9; ++i) mx = fmaxf(mx, d2s[i]);
        float den = 0.f;
        for (int i = 0; i < 9; ++i) den += expf(d2s[i] - mx);
        float w = 1.f - expf(d2s[0] - mx) / den;
        out_score[b] = w * score[b];
    }
}

// ---------------- bilinear upsample 28->224 ----------------
__global__ void k_upsample(const float* __restrict__ ps, float* __restrict__ U) {
    int idx = blockIdx.x * 256 + threadIdx.x;
    if (idx >= B_ * IMG_ * IMG_) return;
    int x = idx % IMG_, y = (idx / IMG_) % IMG_, b = idx / (IMG_ * IMG_);
    float sx = x * 0.125f - 0.4375f, sy = y * 0.125f - 0.4375f;
    int ix = (int)floorf(sx), iy = (int)floorf(sy);
    float fx = sx - ix, fy = sy - iy;
    int x0 = min(max(ix, 0), 27), x1 = min(max(ix + 1, 0), 27);
    int y0 = min(max(iy, 0), 27), y1 = min(max(iy + 1, 0), 27);
    const float* p = ps + b * P_;
    U[idx] = (1.f - fy) * ((1.f - fx) * p[y0 * 28 + x0] + fx * p[y0 * 28 + x1])
           + fy * ((1.f - fx) * p[y1 * 28 + x0] + fx * p[y1 * 28 + x1]);
}

// ---------------- separable gaussian blur, reflect pad ----------------
__global__ void k_blurh(const float* __restrict__ U, float* __restrict__ T) {
    __shared__ float g[KS_];
    __shared__ float gs;
    int tid = threadIdx.x;
    if (tid < KS_) { float d = tid - 16.f; g[tid] = expf(-(d * d) / 32.0f); }
    __syncthreads();
    if (tid == 0) { float s = 0.f; for (int i = 0; i < KS_; ++i) s += g[i]; gs = 1.f / s; }
    __syncthreads();
    int idx = blockIdx.x * 256 + tid;
    if (idx >= B_ * IMG_ * IMG_) return;
    int x = idx % IMG_, rowbase = idx - x;
    float a = 0.f;
    for (int t = 0; t < KS_; ++t) {
        int xx = x + t - 16;
        xx = xx < 0 ? -xx : (xx > 223 ? 446 - xx : xx);
        a += g[t] * U[rowbase + xx];
    }
    T[idx] = a * gs;
}
__global__ void k_blurv(const float* __restrict__ T, float* __restrict__ out) {
    __shared__ float g[KS_];
    __shared__ float gs;
    int tid = threadIdx.x;
    if (tid < KS_) { float d = tid - 16.f; g[tid] = expf(-(d * d) / 32.0f); }
    __syncthreads();
    if (tid == 0) { float s = 0.f; for (int i = 0; i < KS_; ++i) s += g[i]; gs = 1.f / s; }
    __syncthreads();
    int idx = blockIdx.x * 256 + tid;
    if (idx >= B_ * IMG_ * IMG_) return;
    int x = idx % IMG_, y = (idx / IMG_) % IMG_, b = idx / (IMG_ * IMG_);
    float a = 0.f;
    for (int t = 0; t < KS_; ++t) {
        int yy = y + t - 16;
        yy = yy < 0 ? -yy : (yy > 223 ? 446 - yy : yy);
        a += g[t] * T[(b * IMG_ + yy) * IMG_ + x];
    }
    out[idx] = a * gs;
}

// ---------------- launch ----------------
extern "C" void kernel_launch(void* const* d_in, const int* in_sizes, int n_in,
                              void* d_out, int out_size, void* d_ws, size_t ws_size,
                              hipStream_t stream) {
    const float* feat1 = (const float*)d_in[0];
    const float* feat2 = (const float*)d_in[1];
    const float* bank  = (const float*)d_in[2];
    float* out = (float*)d_out;
    char* ws = (char*)d_ws;

    const size_t apack_sz = (size_t)NT_ * K16_ * 4 * 512 * 2;   // 38.5 MB
    const size_t bpack_sz = (size_t)MT2_ * K16_ * 8 * 512 * 2;  // 46.4 MB

    size_t o = 0;
    u16* Ah  = (u16*)(ws + o); o += (size_t)N_ * D_ * 2;
    u16* Al  = (u16*)(ws + o); o += (size_t)N_ * D_ * 2;
    size_t o_Ap = o;
    u16* Aph = (u16*)(ws + o); o += apack_sz;      // pdot aliases (dead after gemm1)
    size_t o_Bp = o;
    u16* Bph = (u16*)(ws + o); o += bpack_sz;      // U/T alias (dead after gexact)
    u16* Bpl = (u16*)(ws + o); o += bpack_sz;
    // scratch union: pooled2 (pre-GEMM) / partf (GEMM phase)
    size_t o_scr = o;
    float* pooled2 = (float*)(ws + o_scr);
    float* partf   = (float*)(ws + o_scr);
    size_t r1 = (size_t)MT2_ * N_ * 4, r2 = (size_t)B_ * C2_ * 196 * 4;
    o += (r1 > r2 ? r1 : r2);
    float* xnorm = (float*)(ws + o); o += (size_t)N_ * 4;
    float* ynorm = (float*)(ws + o); o += (size_t)MPAD_ * 4;
    float* ps    = (float*)(ws + o); o += (size_t)N_ * 4;
    int* candrow = (int*)(ws + o);   o += 512;
    u64* candmin = (u64*)(ws + o);   o += 128 * 8;
    float* dnb   = (float*)(ws + o); o += (size_t)B_ * M_ * 4;
    u64* cand9   = (u64*)(ws + o);   o += 128 * 9 * 8;
    int*   mprow = (int*)(ws + o);   o += 64;
    int*   nnidx = (int*)(ws + o);   o += 64;
    float* score = (float*)(ws + o); o += 64;
    int* support = (int*)(ws + o);   o += 9 * B_ * 4;
    float* pdot  = (float*)(ws + o_Ap);   // 30.9 MB < apack_sz OK... (needs 4*118*128*128*4)
    // pdot needs 30.9 MB but apack is 38.5 MB -> fits
    float* U = (float*)(ws + o_Bp);
    float* T = (float*)(ws + o_Bp + (size_t)B_ * IMG_ * IMG_ * 4);

    k_pool2<<<(B_ * C2_ * H2_ * H2_ + 255) / 256, 256, 0, stream>>>(feat2, pooled2);
    k_bank<<<MPAD_, 192, 0, stream>>>(bank, Bph, Bpl, ynorm);
    k_embed<<<B_ * 28, 256, 0, stream>>>(feat1, pooled2, Ah, Al, Aph, xnorm);
    k_gemm1<<<MT2_ * NT_, 256, 0, stream>>>(Aph, Bph, ynorm, partf);
    k_reduce<<<NT_, 128, 0, stream>>>(partf, xnorm, ps);
    k_cand<<<B_, 256, 0, stream>>>(ps, candrow);
    k_gexact<<<dim3(MT1_, 4), 256, 0, stream>>>(Ah, Al, Bph, Bpl, candrow, pdot);
    k_pickc<<<128, 256, 0, stream>>>(pdot, ynorm, candmin);
    k_pick<<<1, 128, 0, stream>>>(candmin, xnorm, candrow, mprow, nnidx, score);
    k_dnb<<<(M_ + 3) / 4, 256, 0, stream>>>(bank, ynorm, nnidx, dnb);
    k_top9a<<<128, 256, 0, stream>>>(dnb, cand9);
    k_top9b<<<B_, 64, 0, stream>>>(cand9, support);
    k_final<<<B_, 256, 0, stream>>>(Ah, Al, bank, ynorm, xnorm, mprow, support, score,
                                    out + (size_t)B_ * IMG_ * IMG_);
    k_upsample<<<(B_ * IMG_ * IMG_ + 255) / 256, 256, 0, stream>>>(ps, U);
    k_blurh<<<(B_ * IMG_ * IMG_ + 255) / 256, 256, 0, stream>>>(U, T);
    k_blurv<<<(B_ * IMG_ * IMG_ + 255) / 256, 256, 0, stream>>>(T, out);
}

// Round 8
// 1192.080 us; speedup vs baseline: 1.1089x; 1.0513x over previous
//
#include <hip/hip_runtime.h>
#include <stdint.h>

// ---------------- problem constants ----------------
#define B_    16
#define C1_   512
#define C2_   1024
#define H2_   14
#define D_    1536
#define K16_  96           // D / 16
#define P_    784          // 28*28
#define N_    12544        // B_*P_
#define M_    15000
#define MPAD_ 15104        // 59*256 padded bank rows
#define MT1_  118          // 128-wide m tiles (k_gexact)
#define MT2_  59           // 256-wide m tiles (k_gemm1)
#define NT_   98           // patch tiles of 128
#define IMG_  224
#define KS_   33

typedef unsigned short u16;
typedef unsigned int   u32;
typedef unsigned long long u64;

// ---------------- helpers ----------------
__device__ __forceinline__ u16 f2bf(float x) {
    u32 u = __float_as_uint(x);
    u = u + 0x7fffu + ((u >> 16) & 1u);   // RNE
    return (u16)(u >> 16);
}
__device__ __forceinline__ float bf2f(u16 h) {
    return __uint_as_float(((u32)h) << 16);
}
__device__ __forceinline__ u32 ordf(float f) {
    u32 u = __float_as_uint(f);
    return (u & 0x80000000u) ? ~u : (u | 0x80000000u);
}
__device__ __forceinline__ float unordf(u32 o) {
    u32 u = (o & 0x80000000u) ? (o ^ 0x80000000u) : ~o;
    return __uint_as_float(u);
}

// Fragment-packed layouts (32x32x16 bf16 A/B operand order):
//   lane = kh*32 + r32 ; Apack[pt][k16][g:4][lane:64][j:8], Bpack[mt][k16][gb:8][lane:64][j:8]
// Every MFMA fragment = one coalesced 16B/lane load. No LDS in k_gemm1.

// ---------------- avg-pool feat2 -> pooled2 [16,1024,14,14] ----------------
__global__ void k_pool2(const float* __restrict__ feat2, float* __restrict__ pooled2) {
    int idx = blockIdx.x * 256 + threadIdx.x;
    if (idx >= B_ * C2_ * H2_ * H2_) return;
    int x = idx % 14, y = (idx / 14) % 14, bc = idx / 196;
    const float* src = feat2 + (size_t)bc * 196;
    float s = 0.f;
    for (int dy = -1; dy <= 1; ++dy) {
        int yy = y + dy; if (yy < 0 || yy > 13) continue;
        for (int dx = -1; dx <= 1; ++dx) {
            int xx = x + dx; if (xx < 0 || xx > 13) continue;
            s += src[yy * 14 + xx];
        }
    }
    pooled2[idx] = s * (1.f / 9.f);
}

// ---------------- bank split -> fragment-packed hi/lo + norms ----------------
__global__ __launch_bounds__(192)
void k_bank(const float* __restrict__ bank, u16* __restrict__ Bph,
            u16* __restrict__ Bpl, float* __restrict__ ynorm) {
    int m = blockIdx.x, tid = threadIdx.x;
    float nrm = 0.f;
    float v[8];
    if (m < M_) {
        const float4* src = (const float4*)(bank + (size_t)m * D_ + tid * 8);
        float4 a = src[0], b = src[1];
        v[0]=a.x; v[1]=a.y; v[2]=a.z; v[3]=a.w; v[4]=b.x; v[5]=b.y; v[6]=b.z; v[7]=b.w;
#pragma unroll
        for (int i = 0; i < 8; ++i) nrm += v[i] * v[i];
    } else {
#pragma unroll
        for (int i = 0; i < 8; ++i) v[i] = 0.f;
    }
    u32 hw[4], lw[4];
#pragma unroll
    for (int i = 0; i < 4; ++i) {
        u16 h0 = f2bf(v[2*i]),   l0 = f2bf(v[2*i]   - bf2f(h0));
        u16 h1 = f2bf(v[2*i+1]), l1 = f2bf(v[2*i+1] - bf2f(h1));
        hw[i] = (u32)h0 | ((u32)h1 << 16);
        lw[i] = (u32)l0 | ((u32)l1 << 16);
    }
    int c = tid * 8;
    int k16 = c >> 4, kh = (c >> 3) & 1;
    int mt2 = m >> 8, r = m & 255, gb = r >> 5, rA = r & 31;
    size_t off = ((((size_t)mt2 * K16_ + k16) * 8 + gb) * 64 + kh * 32 + rA) * 8;
    *(uint4*)(Bph + off) = make_uint4(hw[0], hw[1], hw[2], hw[3]);
    *(uint4*)(Bpl + off) = make_uint4(lw[0], lw[1], lw[2], lw[3]);
    __shared__ float red[3];
    for (int offr = 32; offr; offr >>= 1) nrm += __shfl_down(nrm, offr, 64);
    int wave = tid >> 6, lane = tid & 63;
    if (lane == 0) red[wave] = nrm;
    __syncthreads();
    if (tid == 0) {
        float t = red[0] + red[1] + red[2];
        ynorm[m] = (m < M_) ? t : __uint_as_float(0x7f800000u);  // +inf pad
    }
}

// ---------------- embedding build: vectorized 8-channel octets ----------------
__device__ __forceinline__ void store8(u16* __restrict__ Ah, u16* __restrict__ Al,
                                       u16* __restrict__ Aph, int n, int colb,
                                       const float* v) {
    u32 hw[4], lw[4];
#pragma unroll
    for (int i = 0; i < 4; ++i) {
        u16 h0 = f2bf(v[2*i]),   l0 = f2bf(v[2*i]   - bf2f(h0));
        u16 h1 = f2bf(v[2*i+1]), l1 = f2bf(v[2*i+1] - bf2f(h1));
        hw[i] = (u32)h0 | ((u32)h1 << 16);
        lw[i] = (u32)l0 | ((u32)l1 << 16);
    }
    size_t off = (size_t)n * D_ + colb;
    *(uint4*)(Ah + off) = make_uint4(hw[0], hw[1], hw[2], hw[3]);
    *(uint4*)(Al + off) = make_uint4(lw[0], lw[1], lw[2], lw[3]);
    int pt = n >> 7, r = n & 127, g = r >> 5, rA = r & 31;
    int k16 = colb >> 4, kh = (colb >> 3) & 1;
    size_t poff = ((((size_t)pt * K16_ + k16) * 4 + g) * 64 + kh * 32 + rA) * 8;
    *(uint4*)(Aph + poff) = make_uint4(hw[0], hw[1], hw[2], hw[3]);
}

__global__ __launch_bounds__(256)
void k_embed(const float* __restrict__ feat1, const float* __restrict__ pooled2,
             u16* __restrict__ Ah, u16* __restrict__ Al, u16* __restrict__ Aph,
             float* __restrict__ xnorm) {
    __shared__ float sF[3 * 64 * 29];   // [r][c][x] padded to 29
    __shared__ float xn[28];
    const int tid = threadIdx.x;
    const int b = blockIdx.x / 28, y = blockIdx.x % 28;
    const int brow = b * P_ + y * 28;
    if (tid < 28) xn[tid] = 0.f;
    const int x = tid >> 3, oct = tid & 7;     // (x, channel-octet)
    const bool act = tid < 224;

    float sy = y * 0.5f - 0.25f;
    int iy = (int)floorf(sy);
    float fy = sy - iy;
    int y0 = min(max(iy, 0), 13), y1 = min(max(iy + 1, 0), 13);
    __syncthreads();

    // ---- feat1 channels (512) in 8 chunks of 64 ----
    for (int cc = 0; cc < 8; ++cc) {
        for (int j = tid; j < 3 * 64 * 28; j += 256) {
            int xx = j % 28, c = (j / 28) % 64, r = j / (28 * 64);
            int yy = y - 1 + r;
            float v = 0.f;
            if (yy >= 0 && yy < 28)
                v = feat1[((size_t)(b * C1_ + cc * 64 + c)) * 784 + yy * 28 + xx];
            sF[(r * 64 + c) * 29 + xx] = v;
        }
        __syncthreads();
        if (act) {
            float v[8]; float nrm = 0.f;
#pragma unroll
            for (int j = 0; j < 8; ++j) {
                int c = oct * 8 + j;
                float s = 0.f;
#pragma unroll
                for (int r = 0; r < 3; ++r) {
                    int base = (r * 64 + c) * 29;
                    if (x > 0) s += sF[base + x - 1];
                    s += sF[base + x];
                    if (x < 27) s += sF[base + x + 1];
                }
                v[j] = s * (1.f / 9.f);
                nrm += v[j] * v[j];
            }
            store8(Ah, Al, Aph, brow + x, cc * 64 + oct * 8, v);
            atomicAdd(&xn[x], nrm);
        }
        __syncthreads();
    }

    // ---- pooled2 channels (1024) in 16 chunks of 64, bilinear ----
    float sx = x * 0.5f - 0.25f;
    int ix = (int)floorf(sx);
    float fx = sx - ix;
    int x0 = min(max(ix, 0), 13), x1 = min(max(ix + 1, 0), 13);
    for (int cc = 0; cc < 16; ++cc) {
        if (act) {
            float v[8]; float nrm = 0.f;
#pragma unroll
            for (int j = 0; j < 8; ++j) {
                int c = cc * 64 + oct * 8 + j;
                const float* sp = pooled2 + ((size_t)(b * C2_ + c)) * 196;
                float vv = (1.f - fy) * ((1.f - fx) * sp[y0 * 14 + x0] + fx * sp[y0 * 14 + x1])
                         + fy * ((1.f - fx) * sp[y1 * 14 + x0] + fx * sp[y1 * 14 + x1]);
                v[j] = vv; nrm += vv * vv;
            }
            store8(Ah, Al, Aph, brow + x, C1_ + cc * 64 + oct * 8, v);
            atomicAdd(&xn[x], nrm);
        }
    }
    __syncthreads();
    if (tid < 28) xnorm[brow + tid] = xn[tid];
}

// ---------------- phase-1: no-LDS GEMM, register-pipelined depth 2 -----------
typedef __bf16 bf16x8 __attribute__((ext_vector_type(8)));
typedef float  f32x16 __attribute__((ext_vector_type(16)));

__global__ __launch_bounds__(256, 2)
void k_gemm1(const u16* __restrict__ Aph, const u16* __restrict__ Bph,
             const float* __restrict__ ynorm, float* __restrict__ partf) {
    __shared__ float smin[128][2];
    const int tid = threadIdx.x, lane = tid & 63, wave = tid >> 6;
    const int GM = 4, nig = GM * NT_;
    const int grp = blockIdx.x / nig, rem = blockIdx.x - grp * nig;
    const int first = grp * GM;
    const int gsz = (MT2_ - first) < GM ? (MT2_ - first) : GM;
    const int mt = first + rem % gsz;
    const int pt = rem / gsz;
    const int p0 = pt * 128, m0 = mt * 256;

    f32x16 acc[2][4];
#pragma unroll
    for (int i = 0; i < 2; ++i)
#pragma unroll
        for (int j = 0; j < 4; ++j)
#pragma unroll
            for (int e = 0; e < 16; ++e) acc[i][j][e] = 0.f;

    const int wr = (wave >> 1) * 64, wc = (wave & 1) * 128;
    const u16* ap = Aph + ((size_t)pt * K16_ * 4 + (wr >> 5)) * 512 + lane * 8;
    const u16* bp = Bph + ((size_t)mt * K16_ * 8 + (wc >> 5)) * 512 + lane * 8;

    bf16x8 af[2][2], bfr[2][4];
#define LOADSET(s) do { \
    af[s][0]  = *(const bf16x8*)(ap); \
    af[s][1]  = *(const bf16x8*)(ap + 512); \
    bfr[s][0] = *(const bf16x8*)(bp); \
    bfr[s][1] = *(const bf16x8*)(bp + 512); \
    bfr[s][2] = *(const bf16x8*)(bp + 1024); \
    bfr[s][3] = *(const bf16x8*)(bp + 1536); \
    ap += 2048; bp += 4096; } while (0)
#define MFMASET(s) do { \
    _Pragma("unroll") \
    for (int ti = 0; ti < 2; ++ti) \
        _Pragma("unroll") \
        for (int tj = 0; tj < 4; ++tj) \
            acc[ti][tj] = __builtin_amdgcn_mfma_f32_32x32x16_bf16( \
                af[s][ti], bfr[s][tj], acc[ti][tj], 0, 0, 0); } while (0)

    LOADSET(0); LOADSET(1);
    for (int k = 0; k < 47; ++k) {     // each iter: 2 k16 steps; loads 2 ahead
        MFMASET(0); LOADSET(0);
        MFMASET(1); LOADSET(1);
    }
    MFMASET(0); MFMASET(1);            // k16 = 94, 95
#undef LOADSET
#undef MFMASET

    // epilogue: C layout (32x32): col = lane&31, row = (reg&3)+8*(reg>>2)+4*kh
    const int c32 = lane & 31, kh = lane >> 5;
    float yn[4];
#pragma unroll
    for (int tj = 0; tj < 4; ++tj) yn[tj] = ynorm[m0 + wc + tj * 32 + c32];
#pragma unroll
    for (int ti = 0; ti < 2; ++ti) {
#pragma unroll
        for (int reg = 0; reg < 16; ++reg) {
            const int rloc = wr + ti * 32 + (reg & 3) + 8 * (reg >> 2) + 4 * kh;
            float v = __uint_as_float(0x7f800000u);
#pragma unroll
            for (int tj = 0; tj < 4; ++tj)
                v = fminf(v, yn[tj] - 2.0f * acc[ti][tj][reg]);
#pragma unroll
            for (int msk = 1; msk < 32; msk <<= 1)
                v = fminf(v, __shfl_xor(v, msk, 64));
            if (c32 == 0) smin[rloc][wave & 1] = v;
        }
    }
    __syncthreads();
    if (tid < 128)
        partf[(size_t)mt * N_ + p0 + tid] = fminf(smin[tid][0], smin[tid][1]);
}

// ---------------- reduce partial mins -> approx patch scores ----------------
__global__ void k_reduce(const float* __restrict__ partf, const float* __restrict__ xnorm,
                         float* __restrict__ ps) {
    int n = blockIdx.x * 128 + threadIdx.x;
    float best = __uint_as_float(0x7f800000u);
    for (int t = 0; t < MT2_; ++t)
        best = fminf(best, partf[(size_t)t * N_ + n]);
    ps[n] = sqrtf(fmaxf(best + xnorm[n], 0.f));
}

// ---------------- per-image approx top-8 patches (candidates) ----------------
__global__ void k_cand(const float* __restrict__ ps, int* __restrict__ candrow) {
    int b = blockIdx.x, tid = threadIdx.x;
    __shared__ u64 red[4];
    u64 prev = ~0ull;
    for (int j = 0; j < 8; ++j) {
        u64 best = 0;
        for (int p = tid; p < P_; p += 256) {
            u64 pk = ((u64)ordf(ps[b * P_ + p]) << 32) | (u32)(~(u32)p);
            if (pk < prev && pk > best) best = pk;
        }
        for (int msk = 1; msk < 64; msk <<= 1) {
            u64 o = __shfl_xor(best, msk, 64);
            best = o > best ? o : best;
        }
        int wave = tid >> 6, lane = tid & 63;
        if (lane == 0) red[wave] = best;
        __syncthreads();
        u64 m = red[0];
        for (int w = 1; w < 4; ++w) m = red[w] > m ? red[w] : m;
        if (tid == 0) candrow[b * 8 + j] = b * P_ + (int)(~(u32)m);
        prev = m;
        __syncthreads();
    }
}

// ---------------- phase-2: exact 3-term split GEMM, SPLIT-K x4 ----------------
#define GLD16(dst, src) __builtin_amdgcn_global_load_lds( \
    (const __attribute__((address_space(1))) void*)(src), \
    (__attribute__((address_space(3))) void*)(dst), 16, 0, 0)

__global__ __launch_bounds__(256)
void k_gexact(const u16* __restrict__ Ah, const u16* __restrict__ Al,
              const u16* __restrict__ Bph, const u16* __restrict__ Bpl,
              const int* __restrict__ candrow, float* __restrict__ pdot) {
    __shared__ u16 sA[2][128 * 32];
    __shared__ int scand[128];

    const int tid = threadIdx.x;
    const int lane = tid & 63, wave = tid >> 6;
    const int mt = blockIdx.x, slice = blockIdx.y;
    if (tid < 128) scand[tid] = candrow[tid];

    f32x16 acc[2][2];
#pragma unroll
    for (int i = 0; i < 2; ++i)
#pragma unroll
        for (int j = 0; j < 2; ++j)
#pragma unroll
            for (int e = 0; e < 16; ++e) acc[i][j][e] = 0.f;

    const int srow = lane >> 2;
    const int scol = ((lane & 3) ^ ((lane >> 3) & 3)) * 8;
    const int wr = (wave >> 1) * 64, wc = (wave & 1) * 64;
    const int rA = lane & 31;
    const int sw = (lane >> 1) & 3;
    const size_t bbase = (((size_t)(mt >> 1) * K16_) * 8 + (mt & 1) * 4 + (wc >> 5)) * 512 + lane * 8;
    __syncthreads();

    for (int kt = slice * 12; kt < slice * 12 + 12; ++kt) {
        const int k0 = kt * 32;
#pragma unroll
        for (int s = 0; s < 2; ++s) {
            const int slab = wave * 2 + s;
            const int row = slab * 16 + srow;
            const int grow = scand[row];
            GLD16(&sA[0][slab * 512], Ah + (size_t)grow * D_ + k0 + scol);
            GLD16(&sA[1][slab * 512], Al + (size_t)grow * D_ + k0 + scol);
        }
        __syncthreads();
#pragma unroll
        for (int ks = 0; ks < 2; ++ks) {
            const int co = ((ks * 2 + (lane >> 5)) ^ sw) * 8;
            const size_t bo = bbase + (size_t)(kt * 2 + ks) * 8 * 512;
            bf16x8 ah0 = *(const bf16x8*)&sA[0][(wr + rA) * 32 + co];
            bf16x8 ah1 = *(const bf16x8*)&sA[0][(wr + 32 + rA) * 32 + co];
            bf16x8 al0 = *(const bf16x8*)&sA[1][(wr + rA) * 32 + co];
            bf16x8 al1 = *(const bf16x8*)&sA[1][(wr + 32 + rA) * 32 + co];
            bf16x8 bh0 = *(const bf16x8*)(Bph + bo);
            bf16x8 bh1 = *(const bf16x8*)(Bph + bo + 512);
            bf16x8 bl0 = *(const bf16x8*)(Bpl + bo);
            bf16x8 bl1 = *(const bf16x8*)(Bpl + bo + 512);
            acc[0][0] = __builtin_amdgcn_mfma_f32_32x32x16_bf16(ah0, bh0, acc[0][0], 0, 0, 0);
            acc[0][1] = __builtin_amdgcn_mfma_f32_32x32x16_bf16(ah0, bh1, acc[0][1], 0, 0, 0);
            acc[1][0] = __builtin_amdgcn_mfma_f32_32x32x16_bf16(ah1, bh0, acc[1][0], 0, 0, 0);
            acc[1][1] = __builtin_amdgcn_mfma_f32_32x32x16_bf16(ah1, bh1, acc[1][1], 0, 0, 0);
            acc[0][0] = __builtin_amdgcn_mfma_f32_32x32x16_bf16(ah0, bl0, acc[0][0], 0, 0, 0);
            acc[0][1] = __builtin_amdgcn_mfma_f32_32x32x16_bf16(ah0, bl1, acc[0][1], 0, 0, 0);
            acc[1][0] = __builtin_amdgcn_mfma_f32_32x32x16_bf16(ah1, bl0, acc[1][0], 0, 0, 0);
            acc[1][1] = __builtin_amdgcn_mfma_f32_32x32x16_bf16(ah1, bl1, acc[1][1], 0, 0, 0);
            acc[0][0] = __builtin_amdgcn_mfma_f32_32x32x16_bf16(al0, bh0, acc[0][0], 0, 0, 0);
            acc[0][1] = __builtin_amdgcn_mfma_f32_32x32x16_bf16(al0, bh1, acc[0][1], 0, 0, 0);
            acc[1][0] = __builtin_amdgcn_mfma_f32_32x32x16_bf16(al1, bh0, acc[1][0], 0, 0, 0);
            acc[1][1] = __builtin_amdgcn_mfma_f32_32x32x16_bf16(al1, bh1, acc[1][1], 0, 0, 0);
        }
        __syncthreads();
    }

    const int wrB = wave >> 1, wcB = wave & 1;
    const int half = lane >> 5, c32 = lane & 31;
    float* base = pdot + ((size_t)(slice * MT1_ + mt) * 128) * 128;
#pragma unroll
    for (int ti = 0; ti < 2; ++ti) {
#pragma unroll
        for (int reg = 0; reg < 16; ++reg) {
            const int rloc = wrB * 64 + ti * 32 + 4 * half + (reg & 3) + 8 * (reg >> 2);
#pragma unroll
            for (int tj = 0; tj < 2; ++tj)
                base[(size_t)rloc * 128 + wcB * 64 + tj * 32 + c32] = acc[ti][tj][reg];
        }
    }
}

// ---------------- per-candidate exact min over all m ----------------
__global__ void k_pickc(const float* __restrict__ pdot, const float* __restrict__ ynorm,
                        u64* __restrict__ candmin) {
    int i = blockIdx.x, tid = threadIdx.x;   // cand index 0..127
    __shared__ u64 red[4];
    u64 best = ~0ull;
    for (int m = tid; m < MPAD_; m += 256) {
        float dot = 0.f;
#pragma unroll
        for (int s = 0; s < 4; ++s)
            dot += pdot[((size_t)(s * MT1_ + (m >> 7)) * 128 + i) * 128 + (m & 127)];
        float v = ynorm[m] - 2.f * dot;
        u64 pk = ((u64)ordf(v) << 32) | (u32)m;
        best = pk < best ? pk : best;
    }
    for (int msk = 1; msk < 64; msk <<= 1) {
        u64 o = __shfl_xor(best, msk, 64);
        best = o < best ? o : best;
    }
    int wave = tid >> 6, lane = tid & 63;
    if (lane == 0) red[wave] = best;
    __syncthreads();
    if (tid == 0) {
        u64 m = red[0];
        for (int w = 1; w < 4; ++w) m = red[w] < m ? red[w] : m;
        candmin[i] = m;
    }
}

// ---------------- pick exact winner per image ----------------
__global__ void k_pick(const u64* __restrict__ candmin, const float* __restrict__ xnorm,
                       const int* __restrict__ candrow, int* __restrict__ mprow,
                       int* __restrict__ nnidx, float* __restrict__ score) {
    __shared__ float sps[128];
    __shared__ int sloc[128];
    int i = threadIdx.x;   // 0..127
    u64 best = candmin[i];
    float val = unordf((u32)(best >> 32)) + xnorm[candrow[i]];
    sps[i] = sqrtf(fmaxf(val, 0.f));
    sloc[i] = (int)(u32)best;
    __syncthreads();
    if (i < B_) {
        float bs = -1.f; int bj = 0; int brw = 1 << 30;
        for (int j = 0; j < 8; ++j) {
            int idx = i * 8 + j;
            float v = sps[idx];
            int row = candrow[idx];
            if (v > bs || (v == bs && row < brw)) { bs = v; bj = idx; brw = row; }
        }
        mprow[i] = brw;
        nnidx[i] = sloc[bj];
        score[i] = bs;
    }
}

// ---------------- d_nb: dist(bank[nn_index[b]], bank) exact fp32 ----------------
__global__ void k_dnb(const float* __restrict__ bank, const float* __restrict__ ynorm,
                      const int* __restrict__ nnidx, float* __restrict__ dnb) {
    int wave = threadIdx.x >> 6, lane = threadIdx.x & 63;
    int m = blockIdx.x * 4 + wave;
    if (m >= M_) return;
    const float4* br = (const float4*)(bank + (size_t)m * D_);
    float acc[B_];
#pragma unroll
    for (int b = 0; b < B_; ++b) acc[b] = 0.f;
#pragma unroll
    for (int p = 0; p < 6; ++p) {
        float4 c = br[p * 64 + lane];
#pragma unroll
        for (int b = 0; b < B_; ++b) {
            const float4* nr = (const float4*)(bank + (size_t)nnidx[b] * D_);
            float4 a = nr[p * 64 + lane];
            acc[b] += a.x * c.x + a.y * c.y + a.z * c.z + a.w * c.w;
        }
    }
    float ym = ynorm[m];
    float keep = 0.f;
#pragma unroll
    for (int b = 0; b < B_; ++b) {
        float v = acc[b];
        for (int msk = 1; msk < 64; msk <<= 1) v += __shfl_xor(v, msk, 64);
        if (lane == b) keep = v;
    }
    if (lane < B_) {
        float ynn = ynorm[nnidx[lane]];
        dnb[lane * M_ + m] = sqrtf(fmaxf(ynn - 2.f * keep + ym, 0.f));
    }
}

// ---------------- top-9 smallest of dnb, two-stage exact ----------------
__global__ void k_top9a(const float* __restrict__ dnb, u64* __restrict__ cand9) {
    int blk = blockIdx.x;            // b*8 + chunk
    int b = blk >> 3, ch = blk & 7;
    int base = ch * 1875;
    int tid = threadIdx.x;
    __shared__ u64 red[4];
    u64 prev = 0;
    for (int p = 0; p < 9; ++p) {
        u64 best = ~0ull;
        for (int i = tid; i < 1875; i += 256) {
            float v = dnb[b * M_ + base + i];
            u64 pk = ((u64)ordf(v) << 32) | (u32)(base + i);
            if (pk > prev && pk < best) best = pk;
        }
        for (int msk = 1; msk < 64; msk <<= 1) {
            u64 o = __shfl_xor(best, msk, 64);
            best = o < best ? o : best;
        }
        int wave = tid >> 6, lane = tid & 63;
        if (lane == 0) red[wave] = best;
        __syncthreads();
        u64 m = red[0];
        for (int w = 1; w < 4; ++w) m = red[w] < m ? red[w] : m;
        if (tid == 0) cand9[blk * 9 + p] = m;
        prev = m;
        __syncthreads();
    }
}
__global__ void k_top9b(const u64* __restrict__ cand9, int* __restrict__ support) {
    int b = blockIdx.x, lane = threadIdx.x;   // 64 threads
    u64 v0 = lane < 72 ? cand9[b * 72 + lane] : ~0ull;
    u64 v1 = (lane + 64) < 72 ? cand9[b * 72 + lane + 64] : ~0ull;
    u64 prev = 0;
    for (int p = 0; p < 9; ++p) {
        u64 best = ~0ull;
        if (v0 > prev && v0 < best) best = v0;
        if (v1 > prev && v1 < best) best = v1;
        for (int msk = 1; msk < 64; msk <<= 1) {
            u64 o = __shfl_xor(best, msk, 64);
            best = o < best ? o : best;
        }
        if (lane == 0) support[b * 9 + p] = (int)(u32)best;
        prev = best;
    }
}

// ---------------- d2 + softmax reweight -> pred_score ----------------
__global__ void k_final(const u16* __restrict__ Ah, const u16* __restrict__ Al,
                        const float* __restrict__ bank, const float* __restrict__ ynorm,
                        const float* __restrict__ xnorm, const int* __restrict__ mprow,
                        const int* __restrict__ support, const float* __restrict__ score,
                        float* __restrict__ out_score) {
    int b = blockIdx.x;
    int wave = threadIdx.x >> 6, lane = threadIdx.x & 63;
    __shared__ float d2s[9];
    int row = mprow[b];
    float xn = xnorm[row];
    for (int s = wave; s < 9; s += 4) {
        int sup = support[b * 9 + s];
        float acc = 0.f;
        for (int p = 0; p < 24; ++p) {
            int k = p * 64 + lane;
            float e = bf2f(Ah[(size_t)row * D_ + k]) + bf2f(Al[(size_t)row * D_ + k]);
            acc += e * bank[(size_t)sup * D_ + k];
        }
        for (int msk = 1; msk < 64; msk <<= 1) acc += __shfl_xor(acc, msk, 64);
        if (lane == 0) d2s[s] = sqrtf(fmaxf(xn - 2.f * acc + ynorm[sup], 0.f));
    }
    __syncthreads();
    if (threadIdx.x == 0) {
        float mx = d2s[0];
        for (int i = 1; i < 9; ++i) mx = fmaxf(mx, d2s[i]);
        float den = 0.f;
        for (int i = 0; i < 9; ++i) den += expf(d2s[i] - mx);
        float w = 1.f - expf(d2s[0] - mx) / den;
        out_score[b] = w * score[b];
    }
}

// ---------------- bilinear upsample 28->224 ----------------
__global__ void k_upsample(const float* __restrict__ ps, float* __restrict__ U) {
    int idx = blockIdx.x * 256 + threadIdx.x;
    if (idx >= B_ * IMG_ * IMG_) return;
    int x = idx % IMG_, y = (idx / IMG_) % IMG_, b = idx / (IMG_ * IMG_);
    float sx = x * 0.125f - 0.4375f, sy = y * 0.125f - 0.4375f;
    int ix = (int)floorf(sx), iy = (int)floorf(sy);
    float fx = sx - ix, fy = sy - iy;
    int x0 = min(max(ix, 0), 27), x1 = min(max(ix + 1, 0), 27);
    int y0 = min(max(iy, 0), 27), y1 = min(max(iy + 1, 0), 27);
    const float* p = ps + b * P_;
    U[idx] = (1.f - fy) * ((1.f - fx) * p[y0 * 28 + x0] + fx * p[y0 * 28 + x1])
           + fy * ((1.f - fx) * p[y1 * 28 + x0] + fx * p[y1 * 28 + x1]);
}

// ---------------- separable gaussian blur, reflect pad ----------------
__global__ void k_blurh(const float* __restrict__ U, float* __restrict__ T) {
    __shared__ float g[KS_];
    __shared__ float gs;
    int tid = threadIdx.x;
    if (tid < KS_) { float d = tid - 16.f; g[tid] = expf(-(d * d) / 32.0f); }
    __syncthreads();
    if (tid == 0) { float s = 0.f; for (int i = 0; i < KS_; ++i) s += g[i]; gs = 1.f / s; }
    __syncthreads();
    int idx = blockIdx.x * 256 + tid;
    if (idx >= B_ * IMG_ * IMG_) return;
    int x = idx % IMG_, rowbase = idx - x;
    float a = 0.f;
    for (int t = 0; t < KS_; ++t) {
        int xx = x + t - 16;
        xx = xx < 0 ? -xx : (xx > 223 ? 446 - xx : xx);
        a += g[t] * U[rowbase + xx];
    }
    T[idx] = a * gs;
}
__global__ void k_blurv(const float* __restrict__ T, float* __restrict__ out) {
    __shared__ float g[KS_];
    __shared__ float gs;
    int tid = threadIdx.x;
    if (tid < KS_) { float d = tid - 16.f; g[tid] = expf(-(d * d) / 32.0f); }
    __syncthreads();
    if (tid == 0) { float s = 0.f; for (int i = 0; i < KS_; ++i) s += g[i]; gs = 1.f / s; }
    __syncthreads();
    int idx = blockIdx.x * 256 + tid;
    if (idx >= B_ * IMG_ * IMG_) return;
    int x = idx % IMG_, y = (idx / IMG_) % IMG_, b = idx / (IMG_ * IMG_);
    float a = 0.f;
    for (int t = 0; t < KS_; ++t) {
        int yy = y + t - 16;
        yy = yy < 0 ? -yy : (yy > 223 ? 446 - yy : yy);
        a += g[t] * T[(b * IMG_ + yy) * IMG_ + x];
    }
    out[idx] = a * gs;
}

// ---------------- launch ----------------
extern "C" void kernel_launch(void* const* d_in, const int* in_sizes, int n_in,
                              void* d_out, int out_size, void* d_ws, size_t ws_size,
                              hipStream_t stream) {
    const float* feat1 = (const float*)d_in[0];
    const float* feat2 = (const float*)d_in[1];
    const float* bank  = (const float*)d_in[2];
    float* out = (float*)d_out;
    char* ws = (char*)d_ws;

    const size_t apack_sz = (size_t)NT_ * K16_ * 4 * 512 * 2;   // 38.5 MB
    const size_t bpack_sz = (size_t)MT2_ * K16_ * 8 * 512 * 2;  // 46.4 MB

    size_t o = 0;
    u16* Ah  = (u16*)(ws + o); o += (size_t)N_ * D_ * 2;
    u16* Al  = (u16*)(ws + o); o += (size_t)N_ * D_ * 2;
    size_t o_Ap = o;
    u16* Aph = (u16*)(ws + o); o += apack_sz;      // pdot aliases (dead after gemm1)
    size_t o_Bp = o;
    u16* Bph = (u16*)(ws + o); o += bpack_sz;      // U/T alias (dead after gexact)
    u16* Bpl = (u16*)(ws + o); o += bpack_sz;
    size_t o_scr = o;
    float* pooled2 = (float*)(ws + o_scr);
    float* partf   = (float*)(ws + o_scr);
    size_t r1 = (size_t)MT2_ * N_ * 4, r2 = (size_t)B_ * C2_ * 196 * 4;
    o += (r1 > r2 ? r1 : r2);
    float* xnorm = (float*)(ws + o); o += (size_t)N_ * 4;
    float* ynorm = (float*)(ws + o); o += (size_t)MPAD_ * 4;
    float* ps    = (float*)(ws + o); o += (size_t)N_ * 4;
    int* candrow = (int*)(ws + o);   o += 512;
    u64* candmin = (u64*)(ws + o);   o += 128 * 8;
    float* dnb   = (float*)(ws + o); o += (size_t)B_ * M_ * 4;
    u64* cand9   = (u64*)(ws + o);   o += 128 * 9 * 8;
    int*   mprow = (int*)(ws + o);   o += 64;
    int*   nnidx = (int*)(ws + o);   o += 64;
    float* score = (float*)(ws + o); o += 64;
    int* support = (int*)(ws + o);   o += 9 * B_ * 4;
    float* pdot  = (float*)(ws + o_Ap);   // 30.9 MB fits in apack region (38.5 MB)
    float* U = (float*)(ws + o_Bp);
    float* T = (float*)(ws + o_Bp + (size_t)B_ * IMG_ * IMG_ * 4);

    k_pool2<<<(B_ * C2_ * H2_ * H2_ + 255) / 256, 256, 0, stream>>>(feat2, pooled2);
    k_bank<<<MPAD_, 192, 0, stream>>>(bank, Bph, Bpl, ynorm);
    k_embed<<<B_ * 28, 256, 0, stream>>>(feat1, pooled2, Ah, Al, Aph, xnorm);
    k_gemm1<<<MT2_ * NT_, 256, 0, stream>>>(Aph, Bph, ynorm, partf);
    k_reduce<<<NT_, 128, 0, stream>>>(partf, xnorm, ps);
    k_cand<<<B_, 256, 0, stream>>>(ps, candrow);
    k_gexact<<<dim3(MT1_, 4), 256, 0, stream>>>(Ah, Al, Bph, Bpl, candrow, pdot);
    k_pickc<<<128, 256, 0, stream>>>(pdot, ynorm, candmin);
    k_pick<<<1, 128, 0, stream>>>(candmin, xnorm, candrow, mprow, nnidx, score);
    k_dnb<<<(M_ + 3) / 4, 256, 0, stream>>>(bank, ynorm, nnidx, dnb);
    k_top9a<<<128, 256, 0, stream>>>(dnb, cand9);
    k_top9b<<<B_, 64, 0, stream>>>(cand9, support);
    k_final<<<B_, 256, 0, stream>>>(Ah, Al, bank, ynorm, xnorm, mprow, support, score,
                                    out + (size_t)B_ * IMG_ * IMG_);
    k_upsample<<<(B_ * IMG_ * IMG_ + 255) / 256, 256, 0, stream>>>(ps, U);
    k_blurh<<<(B_ * IMG_ * IMG_ + 255) / 256, 256, 0, stream>>>(U, T);
    k_blurv<<<(B_ * IMG_ * IMG_ + 255) / 256, 256, 0, stream>>>(T, out);
}